// Round 2
// baseline (1461.903 us; speedup 1.0000x reference)
//
#include <hip/hip_runtime.h>

// RGCN: N=50000, E=600000, D=64, R=65, L=2.
// out_i = relu( sum_r mean_{j in N_r(i)} x_j@W_r + x_i@root + b ) + relu( x_i@res_W + res_b )
// Strategy: counting-sort edges by relation (W reuse in LDS) AND by dst (CSR gather),
// per-edge transform -> bf16 message buffer -> CSR gather-sum fused with node transforms.
// No float atomics anywhere.

constexpr int NN  = 50000;
constexpr int EE  = 600000;
constexpr int DIM = 64;
constexpr int RR  = 65;
constexpr int CHUNK = 256;                    // edges per relation-chunk (one msg_k block)
constexpr int MAXCHUNKS = EE / CHUNK + RR + 8; // sum_r ceil(c_r/256) <= E/256 + R

__device__ inline unsigned short f2bf(float f) {
  unsigned int u = __float_as_uint(f);
  return (unsigned short)((u + 0x7fffu + ((u >> 16) & 1u)) >> 16);  // RNE
}
__device__ inline float bf2f(unsigned short v) {
  return __uint_as_float(((unsigned int)v) << 16);
}

// ---------------- setup (layer-invariant, rebuilt every launch) ----------------

__global__ __launch_bounds__(256) void hist_k(const int* __restrict__ dst,
                                              const int* __restrict__ et,
                                              int* __restrict__ cnt,
                                              int* __restrict__ deg,
                                              int* __restrict__ typecnt, int E) {
  __shared__ int lt[RR];
  for (int i = threadIdx.x; i < RR; i += 256) lt[i] = 0;
  __syncthreads();
  const int e = blockIdx.x * 256 + threadIdx.x;
  if (e < E) {
    const int d = dst[e], r = et[e];
    atomicAdd(&cnt[d * RR + r], 1);
    atomicAdd(&deg[d], 1);
    atomicAdd(&lt[r], 1);
  }
  __syncthreads();
  for (int i = threadIdx.x; i < RR; i += 256)
    if (lt[i]) atomicAdd(&typecnt[i], lt[i]);
}

// exclusive scan of deg[NN] -> rowptr, and init poscur = rowptr
__global__ __launch_bounds__(1024) void scan_node_k(const int* __restrict__ deg,
                                                    int* __restrict__ rowptr,
                                                    int* __restrict__ poscur) {
  __shared__ int s[1024];
  const int t = threadIdx.x;
  const int CH = (NN + 1023) / 1024;  // 49
  const int base = t * CH;
  int sum = 0;
  for (int i = 0; i < CH; ++i) { int idx = base + i; if (idx < NN) sum += deg[idx]; }
  s[t] = sum;
  __syncthreads();
  for (int off = 1; off < 1024; off <<= 1) {
    int v = (t >= off) ? s[t - off] : 0;
    __syncthreads();
    s[t] += v;
    __syncthreads();
  }
  int run = (t > 0) ? s[t - 1] : 0;
  for (int i = 0; i < CH; ++i) {
    int idx = base + i;
    if (idx < NN) { rowptr[idx] = run; poscur[idx] = run; run += deg[idx]; }
  }
  if (t == 1023) rowptr[NN] = EE;
}

// scan 65 type counts (serial, trivial) + emit chunk descriptors {beg,end,rel}
__global__ __launch_bounds__(256) void scan_type_k(const int* __restrict__ typecnt,
                                                   int* __restrict__ tcur,
                                                   int4* __restrict__ chunkArr,
                                                   int* __restrict__ nchunks) {
  __shared__ int tptr[RR + 1];
  if (threadIdx.x == 0) {
    int run = 0;
    for (int r = 0; r < RR; ++r) { tptr[r] = run; tcur[r] = run; run += typecnt[r]; }
    tptr[RR] = run;
  }
  __syncthreads();
  for (int r = threadIdx.x; r < RR; r += 256) {
    for (int c = tptr[r]; c < tptr[r + 1]; c += CHUNK) {
      int idx = atomicAdd(nchunks, 1);
      chunkArr[idx] = make_int4(c, min(c + CHUNK, tptr[r + 1]), r, 0);
    }
  }
}

// scatter edges into type-sorted order; record dst-sorted slot + mean scale
__global__ __launch_bounds__(256) void build_k(const int* __restrict__ src,
                                               const int* __restrict__ dst,
                                               const int* __restrict__ et,
                                               const int* __restrict__ cnt,
                                               int* __restrict__ tcur,
                                               int* __restrict__ poscur,
                                               int* __restrict__ osrc,
                                               int* __restrict__ opos,
                                               float* __restrict__ oscale, int E) {
  const int e = blockIdx.x * 256 + threadIdx.x;
  if (e >= E) return;
  const int s = src[e], d = dst[e], r = et[e];
  const int q = atomicAdd(&tcur[r], 1);
  const int p = atomicAdd(&poscur[d], 1);
  osrc[q] = s;
  opos[q] = p;
  oscale[q] = 1.0f / (float)cnt[d * RR + r];
}

// ---------------- per-layer kernels ----------------

// One block per relation-chunk: W_r staged in LDS, 16-lane groups process 4 edges/batch.
__global__ __launch_bounds__(256) void msg_k(const float* __restrict__ h,
                                             const int* __restrict__ osrc,
                                             const int* __restrict__ opos,
                                             const float* __restrict__ oscale,
                                             const float* __restrict__ W,
                                             const int4* __restrict__ chunkArr,
                                             const int* __restrict__ nchunks,
                                             unsigned short* __restrict__ m) {
  const int ci = blockIdx.x;
  if (ci >= *nchunks) return;
  const int4 c = chunkArr[ci];
  const int beg = c.x, end = c.y, rel = c.z;

  __shared__ float Wlds[DIM * DIM];  // 16 KB
  const float* Wg = W + (size_t)rel * (DIM * DIM);
#pragma unroll
  for (int i = 0; i < 4; ++i)
    *reinterpret_cast<float4*>(&Wlds[i * 1024 + threadIdx.x * 4]) =
        *reinterpret_cast<const float4*>(Wg + i * 1024 + threadIdx.x * 4);
  __syncthreads();

  const int g = threadIdx.x >> 4, li = threadIdx.x & 15;
  __shared__ float xs[16][4][68];

  // group g owns edges [beg + g*16, beg + g*16 + 16), in 4 batches of 4
  for (int b = 0; b < 4; ++b) {
    const int e0 = beg + g * 16 + b * 4;
    const int nvalid = min(4, end - e0);
    if (nvalid <= 0) continue;

#pragma unroll
    for (int r = 0; r < 4; ++r) {
      const int e = e0 + ((r < nvalid) ? r : (nvalid - 1));  // clamp (safe dup)
      const int s = osrc[e];
      *reinterpret_cast<float4*>(&xs[g][r][li * 4]) =
          *reinterpret_cast<const float4*>(h + (size_t)s * DIM + li * 4);
    }

    float acc[4][4];
#pragma unroll
    for (int r = 0; r < 4; ++r) { acc[r][0] = 0.f; acc[r][1] = 0.f; acc[r][2] = 0.f; acc[r][3] = 0.f; }

#pragma unroll 8
    for (int k = 0; k < DIM; ++k) {
      const float4 w = *reinterpret_cast<const float4*>(&Wlds[k * DIM + li * 4]);
#pragma unroll
      for (int r = 0; r < 4; ++r) {
        const float xv = xs[g][r][k];
        acc[r][0] += xv * w.x; acc[r][1] += xv * w.y;
        acc[r][2] += xv * w.z; acc[r][3] += xv * w.w;
      }
    }

    for (int r = 0; r < nvalid; ++r) {
      const int e = e0 + r;
      const float sc = oscale[e];
      ushort4 o;
      o.x = f2bf(acc[r][0] * sc); o.y = f2bf(acc[r][1] * sc);
      o.z = f2bf(acc[r][2] * sc); o.w = f2bf(acc[r][3] * sc);
      *reinterpret_cast<ushort4*>(m + (size_t)opos[e] * DIM + li * 4) = o;
    }
  }
}

// CSR gather of messages + root/residual transforms, fused. 16 lanes per node.
__global__ __launch_bounds__(256) void gather_k(const float* __restrict__ hin,
                                                const unsigned short* __restrict__ m,
                                                const int* __restrict__ rowptr,
                                                const float* __restrict__ root,
                                                const float* __restrict__ bias,
                                                const float* __restrict__ rw,
                                                const float* __restrict__ rb,
                                                float* __restrict__ hout, int N) {
  __shared__ float xs[16][68];
  const int g = threadIdx.x >> 4, li = threadIdx.x & 15;
  const int n = blockIdx.x * 16 + g;
  if (n >= N) return;

  *reinterpret_cast<float4*>(&xs[g][li * 4]) =
      *reinterpret_cast<const float4*>(hin + (size_t)n * DIM + li * 4);

  float a0 = 0.f, a1 = 0.f, a2 = 0.f, a3 = 0.f;
  const int jb = rowptr[n], je = rowptr[n + 1];
  for (int j = jb; j < je; ++j) {
    const ushort4 mv = *reinterpret_cast<const ushort4*>(m + (size_t)j * DIM + li * 4);
    a0 += bf2f(mv.x); a1 += bf2f(mv.y); a2 += bf2f(mv.z); a3 += bf2f(mv.w);
  }

  float r0 = 0.f, r1 = 0.f, r2 = 0.f, r3 = 0.f;
  float s0 = 0.f, s1 = 0.f, s2 = 0.f, s3 = 0.f;
#pragma unroll 8
  for (int k = 0; k < DIM; ++k) {
    const float hd = xs[g][k];
    const float4 w = *reinterpret_cast<const float4*>(root + k * DIM + li * 4);
    const float4 v = *reinterpret_cast<const float4*>(rw + k * DIM + li * 4);
    r0 += hd * w.x; r1 += hd * w.y; r2 += hd * w.z; r3 += hd * w.w;
    s0 += hd * v.x; s1 += hd * v.y; s2 += hd * v.z; s3 += hd * v.w;
  }
  const float4 b = *reinterpret_cast<const float4*>(bias + li * 4);
  const float4 cc = *reinterpret_cast<const float4*>(rb + li * 4);
  float o0 = fmaxf(a0 + r0 + b.x, 0.f) + fmaxf(s0 + cc.x, 0.f);
  float o1 = fmaxf(a1 + r1 + b.y, 0.f) + fmaxf(s1 + cc.y, 0.f);
  float o2 = fmaxf(a2 + r2 + b.z, 0.f) + fmaxf(s2 + cc.z, 0.f);
  float o3 = fmaxf(a3 + r3 + b.w, 0.f) + fmaxf(s3 + cc.w, 0.f);
  *reinterpret_cast<float4*>(hout + (size_t)n * DIM + li * 4) = make_float4(o0, o1, o2, o3);
}

// ---------------- round-1 fallback (float atomics) if ws too small ----------------

__global__ __launch_bounds__(256) void count_k(const int* __restrict__ dst,
                                               const int* __restrict__ et,
                                               int* __restrict__ cnt, int E) {
  int e = blockIdx.x * 256 + threadIdx.x;
  if (e < E) atomicAdd(&cnt[dst[e] * RR + et[e]], 1);
}

__global__ __launch_bounds__(256) void edge_k(const float* __restrict__ h,
                                              const int* __restrict__ src,
                                              const int* __restrict__ dst,
                                              const int* __restrict__ et,
                                              const float* __restrict__ W,
                                              const int* __restrict__ cnt,
                                              float* __restrict__ accum, int E) {
  __shared__ float xs[16][68];
  const int g = threadIdx.x >> 4, li = threadIdx.x & 15;
  const int e = blockIdx.x * 16 + g;
  if (e >= E) return;
  const int s = src[e], d = dst[e], t = et[e];
  *reinterpret_cast<float4*>(&xs[g][li * 4]) =
      *reinterpret_cast<const float4*>(h + (size_t)s * DIM + li * 4);
  const float* Wt = W + (size_t)t * (DIM * DIM) + li * 4;
  float a0 = 0.f, a1 = 0.f, a2 = 0.f, a3 = 0.f;
#pragma unroll 8
  for (int k = 0; k < DIM; ++k) {
    const float xd = xs[g][k];
    const float4 w = *reinterpret_cast<const float4*>(Wt + k * DIM);
    a0 += xd * w.x; a1 += xd * w.y; a2 += xd * w.z; a3 += xd * w.w;
  }
  const float sc = 1.0f / (float)cnt[d * RR + t];
  float* o = accum + (size_t)d * DIM + li * 4;
  unsafeAtomicAdd(o + 0, a0 * sc);
  unsafeAtomicAdd(o + 1, a1 * sc);
  unsafeAtomicAdd(o + 2, a2 * sc);
  unsafeAtomicAdd(o + 3, a3 * sc);
}

__global__ __launch_bounds__(256) void node_k(const float* __restrict__ h,
                                              const float* __restrict__ root,
                                              const float* __restrict__ bias,
                                              const float* __restrict__ rw,
                                              const float* __restrict__ rb,
                                              float* __restrict__ io, int N) {
  __shared__ float xs[16][68];
  const int g = threadIdx.x >> 4, li = threadIdx.x & 15;
  const int n = blockIdx.x * 16 + g;
  if (n >= N) return;
  *reinterpret_cast<float4*>(&xs[g][li * 4]) =
      *reinterpret_cast<const float4*>(h + (size_t)n * DIM + li * 4);
  float r0 = 0.f, r1 = 0.f, r2 = 0.f, r3 = 0.f;
  float s0 = 0.f, s1 = 0.f, s2 = 0.f, s3 = 0.f;
#pragma unroll 8
  for (int k = 0; k < DIM; ++k) {
    const float hd = xs[g][k];
    const float4 w = *reinterpret_cast<const float4*>(root + k * DIM + li * 4);
    const float4 v = *reinterpret_cast<const float4*>(rw + k * DIM + li * 4);
    r0 += hd * w.x; r1 += hd * w.y; r2 += hd * w.z; r3 += hd * w.w;
    s0 += hd * v.x; s1 += hd * v.y; s2 += hd * v.z; s3 += hd * v.w;
  }
  float* o = io + (size_t)n * DIM + li * 4;
  const float4 acc = *reinterpret_cast<const float4*>(o);
  const float4 b = *reinterpret_cast<const float4*>(bias + li * 4);
  const float4 c = *reinterpret_cast<const float4*>(rb + li * 4);
  float o0 = fmaxf(acc.x + r0 + b.x, 0.f) + fmaxf(s0 + c.x, 0.f);
  float o1 = fmaxf(acc.y + r1 + b.y, 0.f) + fmaxf(s1 + c.y, 0.f);
  float o2 = fmaxf(acc.z + r2 + b.z, 0.f) + fmaxf(s2 + c.z, 0.f);
  float o3 = fmaxf(acc.w + r3 + b.w, 0.f) + fmaxf(s3 + c.w, 0.f);
  *reinterpret_cast<float4*>(o) = make_float4(o0, o1, o2, o3);
}

// ---------------- host ----------------

extern "C" void kernel_launch(void* const* d_in, const int* in_sizes, int n_in,
                              void* d_out, int out_size, void* d_ws, size_t ws_size,
                              hipStream_t stream) {
  const float* x    = (const float*)d_in[0];
  const int*   ei   = (const int*)d_in[1];
  const int*   et   = (const int*)d_in[2];
  const float* W    = (const float*)d_in[3];
  const float* root = (const float*)d_in[4];
  const float* bias = (const float*)d_in[5];
  const float* resW = (const float*)d_in[6];
  const float* resb = (const float*)d_in[7];
  float* out = (float*)d_out;

  const int* src = ei;
  const int* dstp = ei + EE;

  char* ws = (char*)d_ws;
  size_t off = 0;
  auto take = [&](size_t bytes) -> void* {
    void* p = ws + off;
    off = (off + bytes + 255) & ~(size_t)255;
    return p;
  };
  unsigned short* m = (unsigned short*)take((size_t)EE * DIM * sizeof(unsigned short));
  float* h1      = (float*)take((size_t)NN * DIM * sizeof(float));
  int* deg       = (int*)take((size_t)NN * sizeof(int));
  int* rowptr    = (int*)take((size_t)(NN + 1) * sizeof(int));
  int* poscur    = (int*)take((size_t)NN * sizeof(int));
  int* typecnt   = (int*)take((size_t)RR * sizeof(int));
  int* tcur      = (int*)take((size_t)RR * sizeof(int));
  int* osrc      = (int*)take((size_t)EE * sizeof(int));
  int* opos      = (int*)take((size_t)EE * sizeof(int));
  float* oscale  = (float*)take((size_t)EE * sizeof(float));
  int4* chunkArr = (int4*)take((size_t)MAXCHUNKS * sizeof(int4));
  int* nchunks   = (int*)take(256);
  int* cnt       = (int*)m;  // alias: cnt only needed before msg_k writes m

  if (off <= ws_size) {
    // ---- sorted path ----
    hipMemsetAsync(cnt, 0, (size_t)NN * RR * sizeof(int), stream);
    hipMemsetAsync(deg, 0, (size_t)NN * sizeof(int), stream);
    hipMemsetAsync(typecnt, 0, (size_t)RR * sizeof(int), stream);
    hipMemsetAsync(nchunks, 0, sizeof(int), stream);

    hist_k<<<(EE + 255) / 256, 256, 0, stream>>>(dstp, et, cnt, deg, typecnt, EE);
    scan_node_k<<<1, 1024, 0, stream>>>(deg, rowptr, poscur);
    scan_type_k<<<1, 256, 0, stream>>>(typecnt, tcur, chunkArr, nchunks);
    build_k<<<(EE + 255) / 256, 256, 0, stream>>>(src, dstp, et, cnt, tcur, poscur,
                                                  osrc, opos, oscale, EE);

    // layer 0: x -> h1
    msg_k<<<MAXCHUNKS, 256, 0, stream>>>(x, osrc, opos, oscale, W, chunkArr, nchunks, m);
    gather_k<<<(NN + 15) / 16, 256, 0, stream>>>(x, m, rowptr, root, bias, resW, resb, h1, NN);
    // layer 1: h1 -> out
    msg_k<<<MAXCHUNKS, 256, 0, stream>>>(h1, osrc, opos, oscale,
                                         W + (size_t)RR * DIM * DIM, chunkArr, nchunks, m);
    gather_k<<<(NN + 15) / 16, 256, 0, stream>>>(h1, m, rowptr, root + DIM * DIM, bias + DIM,
                                                 resW + DIM * DIM, resb + DIM, out, NN);
  } else {
    // ---- fallback: round-1 atomic path (needs only 25.8 MB) ----
    int* fcnt = (int*)ws;
    float* fh1 = (float*)(ws + (size_t)NN * RR * sizeof(int));
    hipMemsetAsync(fcnt, 0, (size_t)NN * RR * sizeof(int), stream);
    hipMemsetAsync(fh1, 0, (size_t)NN * DIM * sizeof(float), stream);
    hipMemsetAsync(out, 0, (size_t)NN * DIM * sizeof(float), stream);
    count_k<<<(EE + 255) / 256, 256, 0, stream>>>(dstp, et, fcnt, EE);
    edge_k<<<(EE + 15) / 16, 256, 0, stream>>>(x, src, dstp, et, W, fcnt, fh1, EE);
    node_k<<<(NN + 15) / 16, 256, 0, stream>>>(x, root, bias, resW, resb, fh1, NN);
    edge_k<<<(EE + 15) / 16, 256, 0, stream>>>(fh1, src, dstp, et,
                                               W + (size_t)RR * DIM * DIM, fcnt, out, EE);
    node_k<<<(NN + 15) / 16, 256, 0, stream>>>(fh1, root + DIM * DIM, bias + DIM,
                                               resW + DIM * DIM, resb + DIM, out, NN);
  }
}

// Round 3
// 539.742 us; speedup vs baseline: 2.7085x; 2.7085x over previous
//
#include <hip/hip_runtime.h>

// RGCN: N=50000, E=600000, D=64, R=65, L=2.
// out_i = relu( sum_r mean_{j in N_r(i)} x_j@W_r + x_i@root + b ) + relu( x_i@res_W + res_b )
// Counting-sort edges by relation (deterministic block-histogram sort, no contended
// atomics) and by dst (low-contention per-node atomic). Per-edge transform with W_r
// staged in LDS -> bf16 message buffer -> CSR gather fused with node transforms.

constexpr int NN  = 50000;
constexpr int EE  = 600000;
constexpr int DIM = 64;
constexpr int RR  = 65;
constexpr int CHUNK = 256;                       // edges per relation-chunk (one msg_k block)
constexpr int MAXCHUNKS = EE / CHUNK + RR + 8;
constexpr int SORT_BS = 4096;                    // edges per sort block
constexpr int NSB = (EE + SORT_BS - 1) / SORT_BS; // 147

__device__ inline unsigned short f2bf(float f) {
  unsigned int u = __float_as_uint(f);
  return (unsigned short)((u + 0x7fffu + ((u >> 16) & 1u)) >> 16);  // RNE
}
__device__ inline float bf2f(unsigned short v) {
  return __uint_as_float(((unsigned int)v) << 16);
}

// ---------------- setup (layer-invariant, rebuilt every launch) ----------------

// Per-block 65-bin type histogram (LDS) + low-contention global histograms.
__global__ __launch_bounds__(256) void hist_k(const int* __restrict__ dst,
                                              const int* __restrict__ et,
                                              int* __restrict__ cnt,
                                              int* __restrict__ deg,
                                              int* __restrict__ bhist, int E) {
  __shared__ int lh[RR];
  for (int i = threadIdx.x; i < RR; i += 256) lh[i] = 0;
  __syncthreads();
  const int base = blockIdx.x * SORT_BS;
  for (int i = threadIdx.x; i < SORT_BS; i += 256) {
    const int e = base + i;
    if (e < E) {
      const int d = dst[e], r = et[e];
      atomicAdd(&lh[r], 1);                  // LDS, block-local
      atomicAdd(&cnt[d * RR + r], 1);        // 3.25M addrs, uncontended
      atomicAdd(&deg[d], 1);                 // 50k addrs, ~12 avg
    }
  }
  __syncthreads();
  for (int i = threadIdx.x; i < RR; i += 256) bhist[blockIdx.x * RR + i] = lh[i];
}

// exclusive scan of deg[NN] -> rowptr, and init poscur = rowptr
__global__ __launch_bounds__(1024) void scan_node_k(const int* __restrict__ deg,
                                                    int* __restrict__ rowptr,
                                                    int* __restrict__ poscur) {
  __shared__ int s[1024];
  const int t = threadIdx.x;
  const int CH = (NN + 1023) / 1024;  // 49
  const int base = t * CH;
  int sum = 0;
  for (int i = 0; i < CH; ++i) { int idx = base + i; if (idx < NN) sum += deg[idx]; }
  s[t] = sum;
  __syncthreads();
  for (int off = 1; off < 1024; off <<= 1) {
    int v = (t >= off) ? s[t - off] : 0;
    __syncthreads();
    s[t] += v;
    __syncthreads();
  }
  int run = (t > 0) ? s[t - 1] : 0;
  for (int i = 0; i < CH; ++i) {
    int idx = base + i;
    if (idx < NN) { rowptr[idx] = run; poscur[idx] = run; run += deg[idx]; }
  }
  if (t == 1023) rowptr[NN] = EE;
}

// Scan bhist bin-major -> per-block bin offsets; emit chunk descriptors. Deterministic.
__global__ __launch_bounds__(128) void scan_type_k(const int* __restrict__ bhist,
                                                   int* __restrict__ boff,
                                                   int4* __restrict__ chunkArr,
                                                   int* __restrict__ nchunks) {
  __shared__ int total[RR], tptr[RR + 1], chbase[RR + 1];
  const int t = threadIdx.x;
  if (t < RR) {
    int s = 0;
    for (int b = 0; b < NSB; ++b) s += bhist[b * RR + t];
    total[t] = s;
  }
  __syncthreads();
  if (t == 0) {
    int run = 0, crun = 0;
    for (int r = 0; r < RR; ++r) {
      tptr[r] = run;   run  += total[r];
      chbase[r] = crun; crun += (total[r] + CHUNK - 1) / CHUNK;
    }
    tptr[RR] = run; chbase[RR] = crun;
    *nchunks = crun;
  }
  __syncthreads();
  if (t < RR) {
    int run = tptr[t];
    for (int b = 0; b < NSB; ++b) { boff[b * RR + t] = run; run += bhist[b * RR + t]; }
    const int nc = (total[t] + CHUNK - 1) / CHUNK;
    for (int i = 0; i < nc; ++i) {
      const int beg = tptr[t] + i * CHUNK;
      chunkArr[chbase[t] + i] = make_int4(beg, min(beg + CHUNK, tptr[t] + total[t]), t, 0);
    }
  }
}

// Re-read block's edges; type-sorted slot from LDS counter (seeded with boff).
__global__ __launch_bounds__(256) void scatter_k(const int* __restrict__ src,
                                                 const int* __restrict__ dst,
                                                 const int* __restrict__ et,
                                                 const int* __restrict__ cnt,
                                                 const int* __restrict__ boff,
                                                 int* __restrict__ poscur,
                                                 int* __restrict__ osrc,
                                                 int* __restrict__ opos,
                                                 float* __restrict__ oscale, int E) {
  __shared__ int cur[RR];
  for (int i = threadIdx.x; i < RR; i += 256) cur[i] = boff[blockIdx.x * RR + i];
  __syncthreads();
  const int base = blockIdx.x * SORT_BS;
  for (int i = threadIdx.x; i < SORT_BS; i += 256) {
    const int e = base + i;
    if (e < E) {
      const int s = src[e], d = dst[e], r = et[e];
      const int q = atomicAdd(&cur[r], 1);       // LDS atomic, block-local
      const int p = atomicAdd(&poscur[d], 1);    // global, ~12 avg contention
      osrc[q] = s;
      opos[q] = p;
      oscale[q] = 1.0f / (float)cnt[d * RR + r];
    }
  }
}

// ---------------- per-layer kernels ----------------

// One block per relation-chunk: W_r staged in LDS, 16-lane groups, 4 edges/batch.
__global__ __launch_bounds__(256) void msg_k(const float* __restrict__ h,
                                             const int* __restrict__ osrc,
                                             const int* __restrict__ opos,
                                             const float* __restrict__ oscale,
                                             const float* __restrict__ W,
                                             const int4* __restrict__ chunkArr,
                                             const int* __restrict__ nchunks,
                                             unsigned short* __restrict__ m) {
  const int ci = blockIdx.x;
  if (ci >= *nchunks) return;
  const int4 c = chunkArr[ci];
  const int beg = c.x, end = c.y, rel = c.z;

  __shared__ float Wlds[DIM * DIM];  // 16 KB
  const float* Wg = W + (size_t)rel * (DIM * DIM);
#pragma unroll
  for (int i = 0; i < 4; ++i)
    *reinterpret_cast<float4*>(&Wlds[i * 1024 + threadIdx.x * 4]) =
        *reinterpret_cast<const float4*>(Wg + i * 1024 + threadIdx.x * 4);
  __syncthreads();

  const int g = threadIdx.x >> 4, li = threadIdx.x & 15;
  __shared__ float xs[16][4][68];

  for (int b = 0; b < 4; ++b) {
    const int e0 = beg + g * 16 + b * 4;
    const int nvalid = min(4, end - e0);
    if (nvalid <= 0) continue;

#pragma unroll
    for (int r = 0; r < 4; ++r) {
      const int e = e0 + ((r < nvalid) ? r : (nvalid - 1));  // clamp (safe dup)
      const int s = osrc[e];
      *reinterpret_cast<float4*>(&xs[g][r][li * 4]) =
          *reinterpret_cast<const float4*>(h + (size_t)s * DIM + li * 4);
    }

    float acc[4][4];
#pragma unroll
    for (int r = 0; r < 4; ++r) { acc[r][0] = 0.f; acc[r][1] = 0.f; acc[r][2] = 0.f; acc[r][3] = 0.f; }

#pragma unroll 8
    for (int k = 0; k < DIM; ++k) {
      const float4 w = *reinterpret_cast<const float4*>(&Wlds[k * DIM + li * 4]);
#pragma unroll
      for (int r = 0; r < 4; ++r) {
        const float xv = xs[g][r][k];
        acc[r][0] += xv * w.x; acc[r][1] += xv * w.y;
        acc[r][2] += xv * w.z; acc[r][3] += xv * w.w;
      }
    }

    for (int r = 0; r < nvalid; ++r) {
      const int e = e0 + r;
      const float sc = oscale[e];
      ushort4 o;
      o.x = f2bf(acc[r][0] * sc); o.y = f2bf(acc[r][1] * sc);
      o.z = f2bf(acc[r][2] * sc); o.w = f2bf(acc[r][3] * sc);
      *reinterpret_cast<ushort4*>(m + (size_t)opos[e] * DIM + li * 4) = o;
    }
  }
}

// CSR gather of messages + root/residual transforms, fused. 16 lanes per node.
__global__ __launch_bounds__(256) void gather_k(const float* __restrict__ hin,
                                                const unsigned short* __restrict__ m,
                                                const int* __restrict__ rowptr,
                                                const float* __restrict__ root,
                                                const float* __restrict__ bias,
                                                const float* __restrict__ rw,
                                                const float* __restrict__ rb,
                                                float* __restrict__ hout, int N) {
  __shared__ float xs[16][68];
  const int g = threadIdx.x >> 4, li = threadIdx.x & 15;
  const int n = blockIdx.x * 16 + g;
  if (n >= N) return;

  *reinterpret_cast<float4*>(&xs[g][li * 4]) =
      *reinterpret_cast<const float4*>(hin + (size_t)n * DIM + li * 4);

  float a0 = 0.f, a1 = 0.f, a2 = 0.f, a3 = 0.f;
  const int jb = rowptr[n], je = rowptr[n + 1];
  for (int j = jb; j < je; ++j) {
    const ushort4 mv = *reinterpret_cast<const ushort4*>(m + (size_t)j * DIM + li * 4);
    a0 += bf2f(mv.x); a1 += bf2f(mv.y); a2 += bf2f(mv.z); a3 += bf2f(mv.w);
  }

  float r0 = 0.f, r1 = 0.f, r2 = 0.f, r3 = 0.f;
  float s0 = 0.f, s1 = 0.f, s2 = 0.f, s3 = 0.f;
#pragma unroll 8
  for (int k = 0; k < DIM; ++k) {
    const float hd = xs[g][k];
    const float4 w = *reinterpret_cast<const float4*>(root + k * DIM + li * 4);
    const float4 v = *reinterpret_cast<const float4*>(rw + k * DIM + li * 4);
    r0 += hd * w.x; r1 += hd * w.y; r2 += hd * w.z; r3 += hd * w.w;
    s0 += hd * v.x; s1 += hd * v.y; s2 += hd * v.z; s3 += hd * v.w;
  }
  const float4 b = *reinterpret_cast<const float4*>(bias + li * 4);
  const float4 cc = *reinterpret_cast<const float4*>(rb + li * 4);
  float o0 = fmaxf(a0 + r0 + b.x, 0.f) + fmaxf(s0 + cc.x, 0.f);
  float o1 = fmaxf(a1 + r1 + b.y, 0.f) + fmaxf(s1 + cc.y, 0.f);
  float o2 = fmaxf(a2 + r2 + b.z, 0.f) + fmaxf(s2 + cc.z, 0.f);
  float o3 = fmaxf(a3 + r3 + b.w, 0.f) + fmaxf(s3 + cc.w, 0.f);
  *reinterpret_cast<float4*>(hout + (size_t)n * DIM + li * 4) = make_float4(o0, o1, o2, o3);
}

// ---------------- fallback (float atomics) if ws too small ----------------

__global__ __launch_bounds__(256) void count_k(const int* __restrict__ dst,
                                               const int* __restrict__ et,
                                               int* __restrict__ cnt, int E) {
  int e = blockIdx.x * 256 + threadIdx.x;
  if (e < E) atomicAdd(&cnt[dst[e] * RR + et[e]], 1);
}

__global__ __launch_bounds__(256) void edge_k(const float* __restrict__ h,
                                              const int* __restrict__ src,
                                              const int* __restrict__ dst,
                                              const int* __restrict__ et,
                                              const float* __restrict__ W,
                                              const int* __restrict__ cnt,
                                              float* __restrict__ accum, int E) {
  __shared__ float xs[16][68];
  const int g = threadIdx.x >> 4, li = threadIdx.x & 15;
  const int e = blockIdx.x * 16 + g;
  if (e >= E) return;
  const int s = src[e], d = dst[e], t = et[e];
  *reinterpret_cast<float4*>(&xs[g][li * 4]) =
      *reinterpret_cast<const float4*>(h + (size_t)s * DIM + li * 4);
  const float* Wt = W + (size_t)t * (DIM * DIM) + li * 4;
  float a0 = 0.f, a1 = 0.f, a2 = 0.f, a3 = 0.f;
#pragma unroll 8
  for (int k = 0; k < DIM; ++k) {
    const float xd = xs[g][k];
    const float4 w = *reinterpret_cast<const float4*>(Wt + k * DIM);
    a0 += xd * w.x; a1 += xd * w.y; a2 += xd * w.z; a3 += xd * w.w;
  }
  const float sc = 1.0f / (float)cnt[d * RR + t];
  float* o = accum + (size_t)d * DIM + li * 4;
  unsafeAtomicAdd(o + 0, a0 * sc);
  unsafeAtomicAdd(o + 1, a1 * sc);
  unsafeAtomicAdd(o + 2, a2 * sc);
  unsafeAtomicAdd(o + 3, a3 * sc);
}

__global__ __launch_bounds__(256) void node_k(const float* __restrict__ h,
                                              const float* __restrict__ root,
                                              const float* __restrict__ bias,
                                              const float* __restrict__ rw,
                                              const float* __restrict__ rb,
                                              float* __restrict__ io, int N) {
  __shared__ float xs[16][68];
  const int g = threadIdx.x >> 4, li = threadIdx.x & 15;
  const int n = blockIdx.x * 16 + g;
  if (n >= N) return;
  *reinterpret_cast<float4*>(&xs[g][li * 4]) =
      *reinterpret_cast<const float4*>(h + (size_t)n * DIM + li * 4);
  float r0 = 0.f, r1 = 0.f, r2 = 0.f, r3 = 0.f;
  float s0 = 0.f, s1 = 0.f, s2 = 0.f, s3 = 0.f;
#pragma unroll 8
  for (int k = 0; k < DIM; ++k) {
    const float hd = xs[g][k];
    const float4 w = *reinterpret_cast<const float4*>(root + k * DIM + li * 4);
    const float4 v = *reinterpret_cast<const float4*>(rw + k * DIM + li * 4);
    r0 += hd * w.x; r1 += hd * w.y; r2 += hd * w.z; r3 += hd * w.w;
    s0 += hd * v.x; s1 += hd * v.y; s2 += hd * v.z; s3 += hd * v.w;
  }
  float* o = io + (size_t)n * DIM + li * 4;
  const float4 acc = *reinterpret_cast<const float4*>(o);
  const float4 b = *reinterpret_cast<const float4*>(bias + li * 4);
  const float4 c = *reinterpret_cast<const float4*>(rb + li * 4);
  float o0 = fmaxf(acc.x + r0 + b.x, 0.f) + fmaxf(s0 + c.x, 0.f);
  float o1 = fmaxf(acc.y + r1 + b.y, 0.f) + fmaxf(s1 + c.y, 0.f);
  float o2 = fmaxf(acc.z + r2 + b.z, 0.f) + fmaxf(s2 + c.z, 0.f);
  float o3 = fmaxf(acc.w + r3 + b.w, 0.f) + fmaxf(s3 + c.w, 0.f);
  *reinterpret_cast<float4*>(o) = make_float4(o0, o1, o2, o3);
}

// ---------------- host ----------------

extern "C" void kernel_launch(void* const* d_in, const int* in_sizes, int n_in,
                              void* d_out, int out_size, void* d_ws, size_t ws_size,
                              hipStream_t stream) {
  const float* x    = (const float*)d_in[0];
  const int*   ei   = (const int*)d_in[1];
  const int*   et   = (const int*)d_in[2];
  const float* W    = (const float*)d_in[3];
  const float* root = (const float*)d_in[4];
  const float* bias = (const float*)d_in[5];
  const float* resW = (const float*)d_in[6];
  const float* resb = (const float*)d_in[7];
  float* out = (float*)d_out;

  const int* src = ei;
  const int* dstp = ei + EE;

  char* ws = (char*)d_ws;
  size_t off = 0;
  auto take = [&](size_t bytes) -> void* {
    void* p = ws + off;
    off = (off + bytes + 255) & ~(size_t)255;
    return p;
  };
  unsigned short* m = (unsigned short*)take((size_t)EE * DIM * sizeof(unsigned short));
  float* h1      = (float*)take((size_t)NN * DIM * sizeof(float));
  int* deg       = (int*)take((size_t)NN * sizeof(int));
  int* rowptr    = (int*)take((size_t)(NN + 1) * sizeof(int));
  int* poscur    = (int*)take((size_t)NN * sizeof(int));
  int* bhist     = (int*)take((size_t)NSB * RR * sizeof(int));
  int* boff      = (int*)take((size_t)NSB * RR * sizeof(int));
  int* osrc      = (int*)take((size_t)EE * sizeof(int));
  int* opos      = (int*)take((size_t)EE * sizeof(int));
  float* oscale  = (float*)take((size_t)EE * sizeof(float));
  int4* chunkArr = (int4*)take((size_t)MAXCHUNKS * sizeof(int4));
  int* nchunks   = (int*)take(256);
  int* cnt       = (int*)m;  // alias: cnt only needed before msg_k writes m

  if (off <= ws_size) {
    // ---- sorted path ----
    hipMemsetAsync(cnt, 0, (size_t)NN * RR * sizeof(int), stream);
    hipMemsetAsync(deg, 0, (size_t)NN * sizeof(int), stream);

    hist_k<<<NSB, 256, 0, stream>>>(dstp, et, cnt, deg, bhist, EE);
    scan_node_k<<<1, 1024, 0, stream>>>(deg, rowptr, poscur);
    scan_type_k<<<1, 128, 0, stream>>>(bhist, boff, chunkArr, nchunks);
    scatter_k<<<NSB, 256, 0, stream>>>(src, dstp, et, cnt, boff, poscur,
                                       osrc, opos, oscale, EE);

    // layer 0: x -> h1
    msg_k<<<MAXCHUNKS, 256, 0, stream>>>(x, osrc, opos, oscale, W, chunkArr, nchunks, m);
    gather_k<<<(NN + 15) / 16, 256, 0, stream>>>(x, m, rowptr, root, bias, resW, resb, h1, NN);
    // layer 1: h1 -> out
    msg_k<<<MAXCHUNKS, 256, 0, stream>>>(h1, osrc, opos, oscale,
                                         W + (size_t)RR * DIM * DIM, chunkArr, nchunks, m);
    gather_k<<<(NN + 15) / 16, 256, 0, stream>>>(h1, m, rowptr, root + DIM * DIM, bias + DIM,
                                                 resW + DIM * DIM, resb + DIM, out, NN);
  } else {
    // ---- fallback: atomic path (needs only 25.8 MB) ----
    int* fcnt = (int*)ws;
    float* fh1 = (float*)(ws + (size_t)NN * RR * sizeof(int));
    hipMemsetAsync(fcnt, 0, (size_t)NN * RR * sizeof(int), stream);
    hipMemsetAsync(fh1, 0, (size_t)NN * DIM * sizeof(float), stream);
    hipMemsetAsync(out, 0, (size_t)NN * DIM * sizeof(float), stream);
    count_k<<<(EE + 255) / 256, 256, 0, stream>>>(dstp, et, fcnt, EE);
    edge_k<<<(EE + 15) / 16, 256, 0, stream>>>(x, src, dstp, et, W, fcnt, fh1, EE);
    node_k<<<(NN + 15) / 16, 256, 0, stream>>>(x, root, bias, resW, resb, fh1, NN);
    edge_k<<<(EE + 15) / 16, 256, 0, stream>>>(fh1, src, dstp, et,
                                               W + (size_t)RR * DIM * DIM, fcnt, out, EE);
    node_k<<<(NN + 15) / 16, 256, 0, stream>>>(fh1, root + DIM * DIM, bias + DIM,
                                               resW + DIM * DIM, resb + DIM, out, NN);
  }
}

// Round 4
// 426.661 us; speedup vs baseline: 3.4264x; 1.2650x over previous
//
#include <hip/hip_runtime.h>

// RGCN: N=50000, E=600000, D=64, R=65, L=2.
// out_i = relu( sum_r mean_{j in N_r(i)} x_j@W_r + x_i@root + b ) + relu( x_i@res_W + res_b )
// Counting-sort edges by relation (deterministic block-histogram sort) and by dst
// (low-contention per-node atomic). Per-edge transform with W_r staged in LDS ->
// bf16 message buffer -> CSR gather fused with node transforms. Parallel 3-kernel
// node-degree scan (round 3's single-block scan was 126 us latency-bound).

constexpr int NN  = 50000;
constexpr int EE  = 600000;
constexpr int DIM = 64;
constexpr int RR  = 65;
constexpr int CHUNK = 256;                        // edges per relation-chunk (one msg_k block)
constexpr int MAXCHUNKS = EE / CHUNK + RR + 8;
constexpr int SORT_BS = 4096;                     // edges per sort block
constexpr int NSB = (EE + SORT_BS - 1) / SORT_BS; // 147
constexpr int SCAN_BS = 1024;
constexpr int SCAN_NB = (NN + SCAN_BS - 1) / SCAN_BS; // 49

__device__ inline unsigned short f2bf(float f) {
  unsigned int u = __float_as_uint(f);
  return (unsigned short)((u + 0x7fffu + ((u >> 16) & 1u)) >> 16);  // RNE
}
__device__ inline float bf2f(unsigned short v) {
  return __uint_as_float(((unsigned int)v) << 16);
}

// ---------------- setup (layer-invariant, rebuilt every launch) ----------------

// Per-block 65-bin type histogram (LDS) + low-contention global histograms.
__global__ __launch_bounds__(256) void hist_k(const int* __restrict__ dst,
                                              const int* __restrict__ et,
                                              int* __restrict__ cnt,
                                              int* __restrict__ deg,
                                              int* __restrict__ bhist, int E) {
  __shared__ int lh[RR];
  for (int i = threadIdx.x; i < RR; i += 256) lh[i] = 0;
  __syncthreads();
  const int base = blockIdx.x * SORT_BS;
  for (int i = threadIdx.x; i < SORT_BS; i += 256) {
    const int e = base + i;
    if (e < E) {
      const int d = dst[e], r = et[e];
      atomicAdd(&lh[r], 1);                  // LDS, block-local
      atomicAdd(&cnt[d * RR + r], 1);        // 3.25M addrs, uncontended
      atomicAdd(&deg[d], 1);                 // 50k addrs, ~12 avg
    }
  }
  __syncthreads();
  for (int i = threadIdx.x; i < RR; i += 256) bhist[blockIdx.x * RR + i] = lh[i];
}

// ---- parallel exclusive scan of deg[NN] -> rowptr, poscur ----

__global__ __launch_bounds__(1024) void scan1_k(const int* __restrict__ deg,
                                                int* __restrict__ bsum) {
  __shared__ int s[SCAN_BS];
  const int idx = blockIdx.x * SCAN_BS + threadIdx.x;
  s[threadIdx.x] = (idx < NN) ? deg[idx] : 0;
  __syncthreads();
  for (int off = SCAN_BS / 2; off > 0; off >>= 1) {
    if (threadIdx.x < off) s[threadIdx.x] += s[threadIdx.x + off];
    __syncthreads();
  }
  if (threadIdx.x == 0) bsum[blockIdx.x] = s[0];
}

__global__ __launch_bounds__(64) void scan2_k(int* __restrict__ bsum) {
  if (threadIdx.x == 0) {
    int run = 0;
    for (int b = 0; b < SCAN_NB; ++b) { const int v = bsum[b]; bsum[b] = run; run += v; }
  }
}

__global__ __launch_bounds__(1024) void scan3_k(const int* __restrict__ deg,
                                                const int* __restrict__ bsum,
                                                int* __restrict__ rowptr,
                                                int* __restrict__ poscur) {
  __shared__ int s[SCAN_BS];
  const int t = threadIdx.x;
  const int idx = blockIdx.x * SCAN_BS + t;
  const int v = (idx < NN) ? deg[idx] : 0;
  s[t] = v;
  __syncthreads();
  for (int off = 1; off < SCAN_BS; off <<= 1) {  // Hillis-Steele inclusive
    const int u = (t >= off) ? s[t - off] : 0;
    __syncthreads();
    s[t] += u;
    __syncthreads();
  }
  const int excl = bsum[blockIdx.x] + s[t] - v;
  if (idx < NN) { rowptr[idx] = excl; poscur[idx] = excl; }
  if (idx == NN - 1) rowptr[NN] = EE;
}

// Scan bhist bin-major -> per-block bin offsets; emit chunk descriptors. Deterministic.
__global__ __launch_bounds__(128) void scan_type_k(const int* __restrict__ bhist,
                                                   int* __restrict__ boff,
                                                   int4* __restrict__ chunkArr,
                                                   int* __restrict__ nchunks) {
  __shared__ int total[RR], tptr[RR + 1], chbase[RR + 1];
  const int t = threadIdx.x;
  if (t < RR) {
    int s = 0;
    for (int b = 0; b < NSB; ++b) s += bhist[b * RR + t];
    total[t] = s;
  }
  __syncthreads();
  if (t == 0) {
    int run = 0, crun = 0;
    for (int r = 0; r < RR; ++r) {
      tptr[r] = run;   run  += total[r];
      chbase[r] = crun; crun += (total[r] + CHUNK - 1) / CHUNK;
    }
    tptr[RR] = run; chbase[RR] = crun;
    *nchunks = crun;
  }
  __syncthreads();
  if (t < RR) {
    int run = tptr[t];
    for (int b = 0; b < NSB; ++b) { boff[b * RR + t] = run; run += bhist[b * RR + t]; }
    const int nc = (total[t] + CHUNK - 1) / CHUNK;
    for (int i = 0; i < nc; ++i) {
      const int beg = tptr[t] + i * CHUNK;
      chunkArr[chbase[t] + i] = make_int4(beg, min(beg + CHUNK, tptr[t] + total[t]), t, 0);
    }
  }
}

// Re-read block's edges; type-sorted slot from LDS counter (seeded with boff).
__global__ __launch_bounds__(256) void scatter_k(const int* __restrict__ src,
                                                 const int* __restrict__ dst,
                                                 const int* __restrict__ et,
                                                 const int* __restrict__ cnt,
                                                 const int* __restrict__ boff,
                                                 int* __restrict__ poscur,
                                                 int* __restrict__ osrc,
                                                 int* __restrict__ opos,
                                                 float* __restrict__ oscale, int E) {
  __shared__ int cur[RR];
  for (int i = threadIdx.x; i < RR; i += 256) cur[i] = boff[blockIdx.x * RR + i];
  __syncthreads();
  const int base = blockIdx.x * SORT_BS;
  for (int i = threadIdx.x; i < SORT_BS; i += 256) {
    const int e = base + i;
    if (e < E) {
      const int s = src[e], d = dst[e], r = et[e];
      const int q = atomicAdd(&cur[r], 1);       // LDS atomic, block-local
      const int p = atomicAdd(&poscur[d], 1);    // global, ~12 avg contention
      osrc[q] = s;
      opos[q] = p;
      oscale[q] = 1.0f / (float)cnt[d * RR + r];
    }
  }
}

// ---------------- per-layer kernels ----------------

// One block per relation-chunk: W_r staged in LDS, 16-lane groups, 4 edges/batch.
__global__ __launch_bounds__(256) void msg_k(const float* __restrict__ h,
                                             const int* __restrict__ osrc,
                                             const int* __restrict__ opos,
                                             const float* __restrict__ oscale,
                                             const float* __restrict__ W,
                                             const int4* __restrict__ chunkArr,
                                             const int* __restrict__ nchunks,
                                             unsigned short* __restrict__ m) {
  const int ci = blockIdx.x;
  if (ci >= *nchunks) return;
  const int4 c = chunkArr[ci];
  const int beg = c.x, end = c.y, rel = c.z;

  __shared__ float Wlds[DIM * DIM];  // 16 KB
  const float* Wg = W + (size_t)rel * (DIM * DIM);
#pragma unroll
  for (int i = 0; i < 4; ++i)
    *reinterpret_cast<float4*>(&Wlds[i * 1024 + threadIdx.x * 4]) =
        *reinterpret_cast<const float4*>(Wg + i * 1024 + threadIdx.x * 4);
  __syncthreads();

  const int g = threadIdx.x >> 4, li = threadIdx.x & 15;
  __shared__ float xs[16][4][68];

  for (int b = 0; b < 4; ++b) {
    const int e0 = beg + g * 16 + b * 4;
    const int nvalid = min(4, end - e0);
    if (nvalid <= 0) continue;

#pragma unroll
    for (int r = 0; r < 4; ++r) {
      const int e = e0 + ((r < nvalid) ? r : (nvalid - 1));  // clamp (safe dup)
      const int s = osrc[e];
      *reinterpret_cast<float4*>(&xs[g][r][li * 4]) =
          *reinterpret_cast<const float4*>(h + (size_t)s * DIM + li * 4);
    }

    float acc[4][4];
#pragma unroll
    for (int r = 0; r < 4; ++r) { acc[r][0] = 0.f; acc[r][1] = 0.f; acc[r][2] = 0.f; acc[r][3] = 0.f; }

#pragma unroll 8
    for (int k = 0; k < DIM; ++k) {
      const float4 w = *reinterpret_cast<const float4*>(&Wlds[k * DIM + li * 4]);
#pragma unroll
      for (int r = 0; r < 4; ++r) {
        const float xv = xs[g][r][k];
        acc[r][0] += xv * w.x; acc[r][1] += xv * w.y;
        acc[r][2] += xv * w.z; acc[r][3] += xv * w.w;
      }
    }

    for (int r = 0; r < nvalid; ++r) {
      const int e = e0 + r;
      const float sc = oscale[e];
      ushort4 o;
      o.x = f2bf(acc[r][0] * sc); o.y = f2bf(acc[r][1] * sc);
      o.z = f2bf(acc[r][2] * sc); o.w = f2bf(acc[r][3] * sc);
      *reinterpret_cast<ushort4*>(m + (size_t)opos[e] * DIM + li * 4) = o;
    }
  }
}

// CSR gather of messages + root/residual transforms, fused. 16 lanes per node.
__global__ __launch_bounds__(256) void gather_k(const float* __restrict__ hin,
                                                const unsigned short* __restrict__ m,
                                                const int* __restrict__ rowptr,
                                                const float* __restrict__ root,
                                                const float* __restrict__ bias,
                                                const float* __restrict__ rw,
                                                const float* __restrict__ rb,
                                                float* __restrict__ hout, int N) {
  __shared__ float xs[16][68];
  const int g = threadIdx.x >> 4, li = threadIdx.x & 15;
  const int n = blockIdx.x * 16 + g;
  if (n >= N) return;

  *reinterpret_cast<float4*>(&xs[g][li * 4]) =
      *reinterpret_cast<const float4*>(hin + (size_t)n * DIM + li * 4);

  float a0 = 0.f, a1 = 0.f, a2 = 0.f, a3 = 0.f;
  const int jb = rowptr[n], je = rowptr[n + 1];
  for (int j = jb; j < je; ++j) {
    const ushort4 mv = *reinterpret_cast<const ushort4*>(m + (size_t)j * DIM + li * 4);
    a0 += bf2f(mv.x); a1 += bf2f(mv.y); a2 += bf2f(mv.z); a3 += bf2f(mv.w);
  }

  float r0 = 0.f, r1 = 0.f, r2 = 0.f, r3 = 0.f;
  float s0 = 0.f, s1 = 0.f, s2 = 0.f, s3 = 0.f;
#pragma unroll 8
  for (int k = 0; k < DIM; ++k) {
    const float hd = xs[g][k];
    const float4 w = *reinterpret_cast<const float4*>(root + k * DIM + li * 4);
    const float4 v = *reinterpret_cast<const float4*>(rw + k * DIM + li * 4);
    r0 += hd * w.x; r1 += hd * w.y; r2 += hd * w.z; r3 += hd * w.w;
    s0 += hd * v.x; s1 += hd * v.y; s2 += hd * v.z; s3 += hd * v.w;
  }
  const float4 b = *reinterpret_cast<const float4*>(bias + li * 4);
  const float4 cc = *reinterpret_cast<const float4*>(rb + li * 4);
  float o0 = fmaxf(a0 + r0 + b.x, 0.f) + fmaxf(s0 + cc.x, 0.f);
  float o1 = fmaxf(a1 + r1 + b.y, 0.f) + fmaxf(s1 + cc.y, 0.f);
  float o2 = fmaxf(a2 + r2 + b.z, 0.f) + fmaxf(s2 + cc.z, 0.f);
  float o3 = fmaxf(a3 + r3 + b.w, 0.f) + fmaxf(s3 + cc.w, 0.f);
  *reinterpret_cast<float4*>(hout + (size_t)n * DIM + li * 4) = make_float4(o0, o1, o2, o3);
}

// ---------------- fallback (float atomics) if ws too small ----------------

__global__ __launch_bounds__(256) void count_k(const int* __restrict__ dst,
                                               const int* __restrict__ et,
                                               int* __restrict__ cnt, int E) {
  int e = blockIdx.x * 256 + threadIdx.x;
  if (e < E) atomicAdd(&cnt[dst[e] * RR + et[e]], 1);
}

__global__ __launch_bounds__(256) void edge_k(const float* __restrict__ h,
                                              const int* __restrict__ src,
                                              const int* __restrict__ dst,
                                              const int* __restrict__ et,
                                              const float* __restrict__ W,
                                              const int* __restrict__ cnt,
                                              float* __restrict__ accum, int E) {
  __shared__ float xs[16][68];
  const int g = threadIdx.x >> 4, li = threadIdx.x & 15;
  const int e = blockIdx.x * 16 + g;
  if (e >= E) return;
  const int s = src[e], d = dst[e], t = et[e];
  *reinterpret_cast<float4*>(&xs[g][li * 4]) =
      *reinterpret_cast<const float4*>(h + (size_t)s * DIM + li * 4);
  const float* Wt = W + (size_t)t * (DIM * DIM) + li * 4;
  float a0 = 0.f, a1 = 0.f, a2 = 0.f, a3 = 0.f;
#pragma unroll 8
  for (int k = 0; k < DIM; ++k) {
    const float xd = xs[g][k];
    const float4 w = *reinterpret_cast<const float4*>(Wt + k * DIM);
    a0 += xd * w.x; a1 += xd * w.y; a2 += xd * w.z; a3 += xd * w.w;
  }
  const float sc = 1.0f / (float)cnt[d * RR + t];
  float* o = accum + (size_t)d * DIM + li * 4;
  unsafeAtomicAdd(o + 0, a0 * sc);
  unsafeAtomicAdd(o + 1, a1 * sc);
  unsafeAtomicAdd(o + 2, a2 * sc);
  unsafeAtomicAdd(o + 3, a3 * sc);
}

__global__ __launch_bounds__(256) void node_k(const float* __restrict__ h,
                                              const float* __restrict__ root,
                                              const float* __restrict__ bias,
                                              const float* __restrict__ rw,
                                              const float* __restrict__ rb,
                                              float* __restrict__ io, int N) {
  __shared__ float xs[16][68];
  const int g = threadIdx.x >> 4, li = threadIdx.x & 15;
  const int n = blockIdx.x * 16 + g;
  if (n >= N) return;
  *reinterpret_cast<float4*>(&xs[g][li * 4]) =
      *reinterpret_cast<const float4*>(h + (size_t)n * DIM + li * 4);
  float r0 = 0.f, r1 = 0.f, r2 = 0.f, r3 = 0.f;
  float s0 = 0.f, s1 = 0.f, s2 = 0.f, s3 = 0.f;
#pragma unroll 8
  for (int k = 0; k < DIM; ++k) {
    const float hd = xs[g][k];
    const float4 w = *reinterpret_cast<const float4*>(root + k * DIM + li * 4);
    const float4 v = *reinterpret_cast<const float4*>(rw + k * DIM + li * 4);
    r0 += hd * w.x; r1 += hd * w.y; r2 += hd * w.z; r3 += hd * w.w;
    s0 += hd * v.x; s1 += hd * v.y; s2 += hd * v.z; s3 += hd * v.w;
  }
  float* o = io + (size_t)n * DIM + li * 4;
  const float4 acc = *reinterpret_cast<const float4*>(o);
  const float4 b = *reinterpret_cast<const float4*>(bias + li * 4);
  const float4 c = *reinterpret_cast<const float4*>(rb + li * 4);
  float o0 = fmaxf(acc.x + r0 + b.x, 0.f) + fmaxf(s0 + c.x, 0.f);
  float o1 = fmaxf(acc.y + r1 + b.y, 0.f) + fmaxf(s1 + c.y, 0.f);
  float o2 = fmaxf(acc.z + r2 + b.z, 0.f) + fmaxf(s2 + c.z, 0.f);
  float o3 = fmaxf(acc.w + r3 + b.w, 0.f) + fmaxf(s3 + c.w, 0.f);
  *reinterpret_cast<float4*>(o) = make_float4(o0, o1, o2, o3);
}

// ---------------- host ----------------

extern "C" void kernel_launch(void* const* d_in, const int* in_sizes, int n_in,
                              void* d_out, int out_size, void* d_ws, size_t ws_size,
                              hipStream_t stream) {
  const float* x    = (const float*)d_in[0];
  const int*   ei   = (const int*)d_in[1];
  const int*   et   = (const int*)d_in[2];
  const float* W    = (const float*)d_in[3];
  const float* root = (const float*)d_in[4];
  const float* bias = (const float*)d_in[5];
  const float* resW = (const float*)d_in[6];
  const float* resb = (const float*)d_in[7];
  float* out = (float*)d_out;

  const int* src = ei;
  const int* dstp = ei + EE;

  char* ws = (char*)d_ws;
  size_t off = 0;
  auto take = [&](size_t bytes) -> void* {
    void* p = ws + off;
    off = (off + bytes + 255) & ~(size_t)255;
    return p;
  };
  unsigned short* m = (unsigned short*)take((size_t)EE * DIM * sizeof(unsigned short));
  float* h1      = (float*)take((size_t)NN * DIM * sizeof(float));
  int* deg       = (int*)take((size_t)NN * sizeof(int));
  int* rowptr    = (int*)take((size_t)(NN + 1) * sizeof(int));
  int* poscur    = (int*)take((size_t)NN * sizeof(int));
  int* bhist     = (int*)take((size_t)NSB * RR * sizeof(int));
  int* boff      = (int*)take((size_t)NSB * RR * sizeof(int));
  int* bsum      = (int*)take((size_t)SCAN_NB * sizeof(int));
  int* osrc      = (int*)take((size_t)EE * sizeof(int));
  int* opos      = (int*)take((size_t)EE * sizeof(int));
  float* oscale  = (float*)take((size_t)EE * sizeof(float));
  int4* chunkArr = (int4*)take((size_t)MAXCHUNKS * sizeof(int4));
  int* nchunks   = (int*)take(256);
  int* cnt       = (int*)m;  // alias: cnt only needed before msg_k writes m

  if (off <= ws_size) {
    // ---- sorted path ----
    hipMemsetAsync(cnt, 0, (size_t)NN * RR * sizeof(int), stream);
    hipMemsetAsync(deg, 0, (size_t)NN * sizeof(int), stream);

    hist_k<<<NSB, 256, 0, stream>>>(dstp, et, cnt, deg, bhist, EE);
    scan1_k<<<SCAN_NB, 1024, 0, stream>>>(deg, bsum);
    scan2_k<<<1, 64, 0, stream>>>(bsum);
    scan3_k<<<SCAN_NB, 1024, 0, stream>>>(deg, bsum, rowptr, poscur);
    scan_type_k<<<1, 128, 0, stream>>>(bhist, boff, chunkArr, nchunks);
    scatter_k<<<NSB, 256, 0, stream>>>(src, dstp, et, cnt, boff, poscur,
                                       osrc, opos, oscale, EE);

    // layer 0: x -> h1
    msg_k<<<MAXCHUNKS, 256, 0, stream>>>(x, osrc, opos, oscale, W, chunkArr, nchunks, m);
    gather_k<<<(NN + 15) / 16, 256, 0, stream>>>(x, m, rowptr, root, bias, resW, resb, h1, NN);
    // layer 1: h1 -> out
    msg_k<<<MAXCHUNKS, 256, 0, stream>>>(h1, osrc, opos, oscale,
                                         W + (size_t)RR * DIM * DIM, chunkArr, nchunks, m);
    gather_k<<<(NN + 15) / 16, 256, 0, stream>>>(h1, m, rowptr, root + DIM * DIM, bias + DIM,
                                                 resW + DIM * DIM, resb + DIM, out, NN);
  } else {
    // ---- fallback: atomic path (needs only 25.8 MB) ----
    int* fcnt = (int*)ws;
    float* fh1 = (float*)(ws + (size_t)NN * RR * sizeof(int));
    hipMemsetAsync(fcnt, 0, (size_t)NN * RR * sizeof(int), stream);
    hipMemsetAsync(fh1, 0, (size_t)NN * DIM * sizeof(float), stream);
    hipMemsetAsync(out, 0, (size_t)NN * DIM * sizeof(float), stream);
    count_k<<<(EE + 255) / 256, 256, 0, stream>>>(dstp, et, fcnt, EE);
    edge_k<<<(EE + 15) / 16, 256, 0, stream>>>(x, src, dstp, et, W, fcnt, fh1, EE);
    node_k<<<(NN + 15) / 16, 256, 0, stream>>>(x, root, bias, resW, resb, fh1, NN);
    edge_k<<<(EE + 15) / 16, 256, 0, stream>>>(fh1, src, dstp, et,
                                               W + (size_t)RR * DIM * DIM, fcnt, out, EE);
    node_k<<<(NN + 15) / 16, 256, 0, stream>>>(fh1, root + DIM * DIM, bias + DIM,
                                               resW + DIM * DIM, resb + DIM, out, NN);
  }
}

// Round 5
// 342.932 us; speedup vs baseline: 4.2630x; 1.2442x over previous
//
#include <hip/hip_runtime.h>

// RGCN: N=50000, E=600000, D=64, R=65, L=2.
// out_i = relu( sum_r mean_{j in N_r(i)} x_j@W_r + x_i@root + b ) + relu( x_i@res_W + res_b )
// Counting-sort edges by relation (block-histogram sort) and by dst (low-contention
// per-node atomic). Per-edge transform with W_r in LDS -> bf16 message buffer ->
// node transform via LDS-staged dense GEMM (xform_k) -> streaming CSR epilogue
// (gather2_k, 4x-unrolled message sum). Round 4's fused gather_k re-read the
// matrices from L1 every k-iter while latency-stalling on the msg loop.

constexpr int NN  = 50000;
constexpr int EE  = 600000;
constexpr int DIM = 64;
constexpr int RR  = 65;
constexpr int CHUNK = 256;                        // edges per relation-chunk (one msg_k block)
constexpr int MAXCHUNKS = EE / CHUNK + RR + 8;
constexpr int SORT_BS = 4096;                     // edges per sort block
constexpr int NSB = (EE + SORT_BS - 1) / SORT_BS; // 147
constexpr int SCAN_BS = 1024;
constexpr int SCAN_NB = (NN + SCAN_BS - 1) / SCAN_BS; // 49
constexpr int XNB = 64;                           // nodes per xform block

__device__ inline unsigned short f2bf(float f) {
  unsigned int u = __float_as_uint(f);
  return (unsigned short)((u + 0x7fffu + ((u >> 16) & 1u)) >> 16);  // RNE
}
__device__ inline float bf2f(unsigned short v) {
  return __uint_as_float(((unsigned int)v) << 16);
}

// ---------------- setup (layer-invariant, rebuilt every launch) ----------------

__global__ __launch_bounds__(256) void hist_k(const int* __restrict__ dst,
                                              const int* __restrict__ et,
                                              int* __restrict__ cnt,
                                              int* __restrict__ deg,
                                              int* __restrict__ bhist, int E) {
  __shared__ int lh[RR];
  for (int i = threadIdx.x; i < RR; i += 256) lh[i] = 0;
  __syncthreads();
  const int base = blockIdx.x * SORT_BS;
  for (int i = threadIdx.x; i < SORT_BS; i += 256) {
    const int e = base + i;
    if (e < E) {
      const int d = dst[e], r = et[e];
      atomicAdd(&lh[r], 1);                  // LDS, block-local
      atomicAdd(&cnt[d * RR + r], 1);        // 3.25M addrs, uncontended
      atomicAdd(&deg[d], 1);                 // 50k addrs, ~12 avg
    }
  }
  __syncthreads();
  for (int i = threadIdx.x; i < RR; i += 256) bhist[blockIdx.x * RR + i] = lh[i];
}

// ---- parallel exclusive scan of deg[NN] -> rowptr, poscur ----

__global__ __launch_bounds__(1024) void scan1_k(const int* __restrict__ deg,
                                                int* __restrict__ bsum) {
  __shared__ int s[SCAN_BS];
  const int idx = blockIdx.x * SCAN_BS + threadIdx.x;
  s[threadIdx.x] = (idx < NN) ? deg[idx] : 0;
  __syncthreads();
  for (int off = SCAN_BS / 2; off > 0; off >>= 1) {
    if (threadIdx.x < off) s[threadIdx.x] += s[threadIdx.x + off];
    __syncthreads();
  }
  if (threadIdx.x == 0) bsum[blockIdx.x] = s[0];
}

__global__ __launch_bounds__(64) void scan2_k(int* __restrict__ bsum) {
  if (threadIdx.x == 0) {
    int run = 0;
    for (int b = 0; b < SCAN_NB; ++b) { const int v = bsum[b]; bsum[b] = run; run += v; }
  }
}

__global__ __launch_bounds__(1024) void scan3_k(const int* __restrict__ deg,
                                                const int* __restrict__ bsum,
                                                int* __restrict__ rowptr,
                                                int* __restrict__ poscur) {
  __shared__ int s[SCAN_BS];
  const int t = threadIdx.x;
  const int idx = blockIdx.x * SCAN_BS + t;
  const int v = (idx < NN) ? deg[idx] : 0;
  s[t] = v;
  __syncthreads();
  for (int off = 1; off < SCAN_BS; off <<= 1) {  // Hillis-Steele inclusive
    const int u = (t >= off) ? s[t - off] : 0;
    __syncthreads();
    s[t] += u;
    __syncthreads();
  }
  const int excl = bsum[blockIdx.x] + s[t] - v;
  if (idx < NN) { rowptr[idx] = excl; poscur[idx] = excl; }
  if (idx == NN - 1) rowptr[NN] = EE;
}

__global__ __launch_bounds__(128) void scan_type_k(const int* __restrict__ bhist,
                                                   int* __restrict__ boff,
                                                   int4* __restrict__ chunkArr,
                                                   int* __restrict__ nchunks) {
  __shared__ int total[RR], tptr[RR + 1], chbase[RR + 1];
  const int t = threadIdx.x;
  if (t < RR) {
    int s = 0;
    for (int b = 0; b < NSB; ++b) s += bhist[b * RR + t];
    total[t] = s;
  }
  __syncthreads();
  if (t == 0) {
    int run = 0, crun = 0;
    for (int r = 0; r < RR; ++r) {
      tptr[r] = run;   run  += total[r];
      chbase[r] = crun; crun += (total[r] + CHUNK - 1) / CHUNK;
    }
    tptr[RR] = run; chbase[RR] = crun;
    *nchunks = crun;
  }
  __syncthreads();
  if (t < RR) {
    int run = tptr[t];
    for (int b = 0; b < NSB; ++b) { boff[b * RR + t] = run; run += bhist[b * RR + t]; }
    const int nc = (total[t] + CHUNK - 1) / CHUNK;
    for (int i = 0; i < nc; ++i) {
      const int beg = tptr[t] + i * CHUNK;
      chunkArr[chbase[t] + i] = make_int4(beg, min(beg + CHUNK, tptr[t] + total[t]), t, 0);
    }
  }
}

__global__ __launch_bounds__(256) void scatter_k(const int* __restrict__ src,
                                                 const int* __restrict__ dst,
                                                 const int* __restrict__ et,
                                                 const int* __restrict__ cnt,
                                                 const int* __restrict__ boff,
                                                 int* __restrict__ poscur,
                                                 int* __restrict__ osrc,
                                                 int* __restrict__ opos,
                                                 float* __restrict__ oscale, int E) {
  __shared__ int cur[RR];
  for (int i = threadIdx.x; i < RR; i += 256) cur[i] = boff[blockIdx.x * RR + i];
  __syncthreads();
  const int base = blockIdx.x * SORT_BS;
  for (int i = threadIdx.x; i < SORT_BS; i += 256) {
    const int e = base + i;
    if (e < E) {
      const int s = src[e], d = dst[e], r = et[e];
      const int q = atomicAdd(&cur[r], 1);       // LDS atomic, block-local
      const int p = atomicAdd(&poscur[d], 1);    // global, ~12 avg contention
      osrc[q] = s;
      opos[q] = p;
      oscale[q] = 1.0f / (float)cnt[d * RR + r];
    }
  }
}

// ---------------- per-layer kernels ----------------

// One block per relation-chunk: W_r staged in LDS, 16-lane groups, 4 edges/batch.
__global__ __launch_bounds__(256) void msg_k(const float* __restrict__ h,
                                             const int* __restrict__ osrc,
                                             const int* __restrict__ opos,
                                             const float* __restrict__ oscale,
                                             const float* __restrict__ W,
                                             const int4* __restrict__ chunkArr,
                                             const int* __restrict__ nchunks,
                                             unsigned short* __restrict__ m) {
  const int ci = blockIdx.x;
  if (ci >= *nchunks) return;
  const int4 c = chunkArr[ci];
  const int beg = c.x, end = c.y, rel = c.z;

  __shared__ float Wlds[DIM * DIM];  // 16 KB
  const float* Wg = W + (size_t)rel * (DIM * DIM);
#pragma unroll
  for (int i = 0; i < 4; ++i)
    *reinterpret_cast<float4*>(&Wlds[i * 1024 + threadIdx.x * 4]) =
        *reinterpret_cast<const float4*>(Wg + i * 1024 + threadIdx.x * 4);
  __syncthreads();

  const int g = threadIdx.x >> 4, li = threadIdx.x & 15;
  __shared__ float xs[16][4][68];

  for (int b = 0; b < 4; ++b) {
    const int e0 = beg + g * 16 + b * 4;
    const int nvalid = min(4, end - e0);
    if (nvalid <= 0) continue;

#pragma unroll
    for (int r = 0; r < 4; ++r) {
      const int e = e0 + ((r < nvalid) ? r : (nvalid - 1));  // clamp (safe dup)
      const int s = osrc[e];
      *reinterpret_cast<float4*>(&xs[g][r][li * 4]) =
          *reinterpret_cast<const float4*>(h + (size_t)s * DIM + li * 4);
    }

    float acc[4][4];
#pragma unroll
    for (int r = 0; r < 4; ++r) { acc[r][0] = 0.f; acc[r][1] = 0.f; acc[r][2] = 0.f; acc[r][3] = 0.f; }

#pragma unroll 8
    for (int k = 0; k < DIM; ++k) {
      const float4 w = *reinterpret_cast<const float4*>(&Wlds[k * DIM + li * 4]);
#pragma unroll
      for (int r = 0; r < 4; ++r) {
        const float xv = xs[g][r][k];
        acc[r][0] += xv * w.x; acc[r][1] += xv * w.y;
        acc[r][2] += xv * w.z; acc[r][3] += xv * w.w;
      }
    }

    for (int r = 0; r < nvalid; ++r) {
      const int e = e0 + r;
      const float sc = oscale[e];
      ushort4 o;
      o.x = f2bf(acc[r][0] * sc); o.y = f2bf(acc[r][1] * sc);
      o.z = f2bf(acc[r][2] * sc); o.w = f2bf(acc[r][3] * sc);
      *reinterpret_cast<ushort4*>(m + (size_t)opos[e] * DIM + li * 4) = o;
    }
  }
}

// Dense node transform: rt = h@root + b, rs = relu(h@rw + rb). Both matrices in LDS.
// 64 nodes/block; group g owns 4 nodes, lane li owns 4 cols; 32 FMA per 2 LDS w-loads.
__global__ __launch_bounds__(256) void xform_k(const float* __restrict__ h,
                                               const float* __restrict__ root,
                                               const float* __restrict__ bias,
                                               const float* __restrict__ rw,
                                               const float* __restrict__ rb,
                                               float* __restrict__ rt,
                                               float* __restrict__ rs, int N) {
  __shared__ float Wl0[DIM * DIM];   // root, 16 KB
  __shared__ float Wl1[DIM * DIM];   // rw,   16 KB
  __shared__ float xs[XNB][68];      // 17 KB
#pragma unroll
  for (int i = 0; i < 4; ++i) {
    reinterpret_cast<float4*>(Wl0)[threadIdx.x + i * 256] =
        reinterpret_cast<const float4*>(root)[threadIdx.x + i * 256];
    reinterpret_cast<float4*>(Wl1)[threadIdx.x + i * 256] =
        reinterpret_cast<const float4*>(rw)[threadIdx.x + i * 256];
  }

  const int g = threadIdx.x >> 4, li = threadIdx.x & 15;
  const int base = blockIdx.x * XNB;
#pragma unroll
  for (int r = 0; r < 4; ++r) {
    const int n = base + g * 4 + r;
    float4 v = make_float4(0.f, 0.f, 0.f, 0.f);
    if (n < N) v = *reinterpret_cast<const float4*>(h + (size_t)n * DIM + li * 4);
    *reinterpret_cast<float4*>(&xs[g * 4 + r][li * 4]) = v;
  }
  __syncthreads();

  float aR[4][4], aS[4][4];
#pragma unroll
  for (int r = 0; r < 4; ++r)
#pragma unroll
    for (int q = 0; q < 4; ++q) { aR[r][q] = 0.f; aS[r][q] = 0.f; }

#pragma unroll 4
  for (int k = 0; k < DIM; ++k) {
    const float4 wr = *reinterpret_cast<const float4*>(&Wl0[k * DIM + li * 4]);
    const float4 wv = *reinterpret_cast<const float4*>(&Wl1[k * DIM + li * 4]);
#pragma unroll
    for (int r = 0; r < 4; ++r) {
      const float xv = xs[g * 4 + r][k];
      aR[r][0] += xv * wr.x; aR[r][1] += xv * wr.y; aR[r][2] += xv * wr.z; aR[r][3] += xv * wr.w;
      aS[r][0] += xv * wv.x; aS[r][1] += xv * wv.y; aS[r][2] += xv * wv.z; aS[r][3] += xv * wv.w;
    }
  }

  const float4 bv = reinterpret_cast<const float4*>(bias)[li];
  const float4 cv = reinterpret_cast<const float4*>(rb)[li];
#pragma unroll
  for (int r = 0; r < 4; ++r) {
    const int n = base + g * 4 + r;
    if (n < N) {
      *reinterpret_cast<float4*>(rt + (size_t)n * DIM + li * 4) =
          make_float4(aR[r][0] + bv.x, aR[r][1] + bv.y, aR[r][2] + bv.z, aR[r][3] + bv.w);
      *reinterpret_cast<float4*>(rs + (size_t)n * DIM + li * 4) =
          make_float4(fmaxf(aS[r][0] + cv.x, 0.f), fmaxf(aS[r][1] + cv.y, 0.f),
                      fmaxf(aS[r][2] + cv.z, 0.f), fmaxf(aS[r][3] + cv.w, 0.f));
    }
  }
}

// Streaming epilogue: hout = relu(sum(msgs) + rt) + rs. Msg loop unrolled 4x.
__global__ __launch_bounds__(256) void gather2_k(const unsigned short* __restrict__ m,
                                                 const int* __restrict__ rowptr,
                                                 const float* __restrict__ rt,
                                                 const float* __restrict__ rs,
                                                 float* __restrict__ hout, int N) {
  const int g = threadIdx.x >> 4, li = threadIdx.x & 15;
  const int n = blockIdx.x * 16 + g;
  if (n >= N) return;

  float a0 = 0.f, a1 = 0.f, a2 = 0.f, a3 = 0.f;
  const int jb = rowptr[n], je = rowptr[n + 1];
  int j = jb;
  for (; j + 4 <= je; j += 4) {            // 4 independent loads in flight
    const ushort4 v0 = *reinterpret_cast<const ushort4*>(m + (size_t)(j + 0) * DIM + li * 4);
    const ushort4 v1 = *reinterpret_cast<const ushort4*>(m + (size_t)(j + 1) * DIM + li * 4);
    const ushort4 v2 = *reinterpret_cast<const ushort4*>(m + (size_t)(j + 2) * DIM + li * 4);
    const ushort4 v3 = *reinterpret_cast<const ushort4*>(m + (size_t)(j + 3) * DIM + li * 4);
    a0 += bf2f(v0.x) + bf2f(v1.x) + bf2f(v2.x) + bf2f(v3.x);
    a1 += bf2f(v0.y) + bf2f(v1.y) + bf2f(v2.y) + bf2f(v3.y);
    a2 += bf2f(v0.z) + bf2f(v1.z) + bf2f(v2.z) + bf2f(v3.z);
    a3 += bf2f(v0.w) + bf2f(v1.w) + bf2f(v2.w) + bf2f(v3.w);
  }
  for (; j < je; ++j) {
    const ushort4 v = *reinterpret_cast<const ushort4*>(m + (size_t)j * DIM + li * 4);
    a0 += bf2f(v.x); a1 += bf2f(v.y); a2 += bf2f(v.z); a3 += bf2f(v.w);
  }

  const float4 t = *reinterpret_cast<const float4*>(rt + (size_t)n * DIM + li * 4);
  const float4 s = *reinterpret_cast<const float4*>(rs + (size_t)n * DIM + li * 4);
  *reinterpret_cast<float4*>(hout + (size_t)n * DIM + li * 4) =
      make_float4(fmaxf(a0 + t.x, 0.f) + s.x, fmaxf(a1 + t.y, 0.f) + s.y,
                  fmaxf(a2 + t.z, 0.f) + s.z, fmaxf(a3 + t.w, 0.f) + s.w);
}

// Fused fallback gather (round-4 path, used if ws lacks room for rt/rs).
__global__ __launch_bounds__(256) void gather_k(const float* __restrict__ hin,
                                                const unsigned short* __restrict__ m,
                                                const int* __restrict__ rowptr,
                                                const float* __restrict__ root,
                                                const float* __restrict__ bias,
                                                const float* __restrict__ rw,
                                                const float* __restrict__ rb,
                                                float* __restrict__ hout, int N) {
  __shared__ float xs[16][68];
  const int g = threadIdx.x >> 4, li = threadIdx.x & 15;
  const int n = blockIdx.x * 16 + g;
  if (n >= N) return;

  *reinterpret_cast<float4*>(&xs[g][li * 4]) =
      *reinterpret_cast<const float4*>(hin + (size_t)n * DIM + li * 4);

  float a0 = 0.f, a1 = 0.f, a2 = 0.f, a3 = 0.f;
  const int jb = rowptr[n], je = rowptr[n + 1];
  for (int j = jb; j < je; ++j) {
    const ushort4 mv = *reinterpret_cast<const ushort4*>(m + (size_t)j * DIM + li * 4);
    a0 += bf2f(mv.x); a1 += bf2f(mv.y); a2 += bf2f(mv.z); a3 += bf2f(mv.w);
  }

  float r0 = 0.f, r1 = 0.f, r2 = 0.f, r3 = 0.f;
  float s0 = 0.f, s1 = 0.f, s2 = 0.f, s3 = 0.f;
#pragma unroll 8
  for (int k = 0; k < DIM; ++k) {
    const float hd = xs[g][k];
    const float4 w = *reinterpret_cast<const float4*>(root + k * DIM + li * 4);
    const float4 v = *reinterpret_cast<const float4*>(rw + k * DIM + li * 4);
    r0 += hd * w.x; r1 += hd * w.y; r2 += hd * w.z; r3 += hd * w.w;
    s0 += hd * v.x; s1 += hd * v.y; s2 += hd * v.z; s3 += hd * v.w;
  }
  const float4 b = *reinterpret_cast<const float4*>(bias + li * 4);
  const float4 cc = *reinterpret_cast<const float4*>(rb + li * 4);
  float o0 = fmaxf(a0 + r0 + b.x, 0.f) + fmaxf(s0 + cc.x, 0.f);
  float o1 = fmaxf(a1 + r1 + b.y, 0.f) + fmaxf(s1 + cc.y, 0.f);
  float o2 = fmaxf(a2 + r2 + b.z, 0.f) + fmaxf(s2 + cc.z, 0.f);
  float o3 = fmaxf(a3 + r3 + b.w, 0.f) + fmaxf(s3 + cc.w, 0.f);
  *reinterpret_cast<float4*>(hout + (size_t)n * DIM + li * 4) = make_float4(o0, o1, o2, o3);
}

// ---------------- last-resort fallback (float atomics) ----------------

__global__ __launch_bounds__(256) void count_k(const int* __restrict__ dst,
                                               const int* __restrict__ et,
                                               int* __restrict__ cnt, int E) {
  int e = blockIdx.x * 256 + threadIdx.x;
  if (e < E) atomicAdd(&cnt[dst[e] * RR + et[e]], 1);
}

__global__ __launch_bounds__(256) void edge_k(const float* __restrict__ h,
                                              const int* __restrict__ src,
                                              const int* __restrict__ dst,
                                              const int* __restrict__ et,
                                              const float* __restrict__ W,
                                              const int* __restrict__ cnt,
                                              float* __restrict__ accum, int E) {
  __shared__ float xs[16][68];
  const int g = threadIdx.x >> 4, li = threadIdx.x & 15;
  const int e = blockIdx.x * 16 + g;
  if (e >= E) return;
  const int s = src[e], d = dst[e], t = et[e];
  *reinterpret_cast<float4*>(&xs[g][li * 4]) =
      *reinterpret_cast<const float4*>(h + (size_t)s * DIM + li * 4);
  const float* Wt = W + (size_t)t * (DIM * DIM) + li * 4;
  float a0 = 0.f, a1 = 0.f, a2 = 0.f, a3 = 0.f;
#pragma unroll 8
  for (int k = 0; k < DIM; ++k) {
    const float xd = xs[g][k];
    const float4 w = *reinterpret_cast<const float4*>(Wt + k * DIM);
    a0 += xd * w.x; a1 += xd * w.y; a2 += xd * w.z; a3 += xd * w.w;
  }
  const float sc = 1.0f / (float)cnt[d * RR + t];
  float* o = accum + (size_t)d * DIM + li * 4;
  unsafeAtomicAdd(o + 0, a0 * sc);
  unsafeAtomicAdd(o + 1, a1 * sc);
  unsafeAtomicAdd(o + 2, a2 * sc);
  unsafeAtomicAdd(o + 3, a3 * sc);
}

__global__ __launch_bounds__(256) void node_k(const float* __restrict__ h,
                                              const float* __restrict__ root,
                                              const float* __restrict__ bias,
                                              const float* __restrict__ rw,
                                              const float* __restrict__ rb,
                                              float* __restrict__ io, int N) {
  __shared__ float xs[16][68];
  const int g = threadIdx.x >> 4, li = threadIdx.x & 15;
  const int n = blockIdx.x * 16 + g;
  if (n >= N) return;
  *reinterpret_cast<float4*>(&xs[g][li * 4]) =
      *reinterpret_cast<const float4*>(h + (size_t)n * DIM + li * 4);
  float r0 = 0.f, r1 = 0.f, r2 = 0.f, r3 = 0.f;
  float s0 = 0.f, s1 = 0.f, s2 = 0.f, s3 = 0.f;
#pragma unroll 8
  for (int k = 0; k < DIM; ++k) {
    const float hd = xs[g][k];
    const float4 w = *reinterpret_cast<const float4*>(root + k * DIM + li * 4);
    const float4 v = *reinterpret_cast<const float4*>(rw + k * DIM + li * 4);
    r0 += hd * w.x; r1 += hd * w.y; r2 += hd * w.z; r3 += hd * w.w;
    s0 += hd * v.x; s1 += hd * v.y; s2 += hd * v.z; s3 += hd * v.w;
  }
  float* o = io + (size_t)n * DIM + li * 4;
  const float4 acc = *reinterpret_cast<const float4*>(o);
  const float4 b = *reinterpret_cast<const float4*>(bias + li * 4);
  const float4 c = *reinterpret_cast<const float4*>(rb + li * 4);
  float o0 = fmaxf(acc.x + r0 + b.x, 0.f) + fmaxf(s0 + c.x, 0.f);
  float o1 = fmaxf(acc.y + r1 + b.y, 0.f) + fmaxf(s1 + c.y, 0.f);
  float o2 = fmaxf(acc.z + r2 + b.z, 0.f) + fmaxf(s2 + c.z, 0.f);
  float o3 = fmaxf(acc.w + r3 + b.w, 0.f) + fmaxf(s3 + c.w, 0.f);
  *reinterpret_cast<float4*>(o) = make_float4(o0, o1, o2, o3);
}

// ---------------- host ----------------

extern "C" void kernel_launch(void* const* d_in, const int* in_sizes, int n_in,
                              void* d_out, int out_size, void* d_ws, size_t ws_size,
                              hipStream_t stream) {
  const float* x    = (const float*)d_in[0];
  const int*   ei   = (const int*)d_in[1];
  const int*   et   = (const int*)d_in[2];
  const float* W    = (const float*)d_in[3];
  const float* root = (const float*)d_in[4];
  const float* bias = (const float*)d_in[5];
  const float* resW = (const float*)d_in[6];
  const float* resb = (const float*)d_in[7];
  float* out = (float*)d_out;

  const int* src = ei;
  const int* dstp = ei + EE;

  char* ws = (char*)d_ws;
  size_t off = 0;
  auto take = [&](size_t bytes) -> void* {
    void* p = ws + off;
    off = (off + bytes + 255) & ~(size_t)255;
    return p;
  };
  unsigned short* m = (unsigned short*)take((size_t)EE * DIM * sizeof(unsigned short));
  float* h1      = (float*)take((size_t)NN * DIM * sizeof(float));
  int* deg       = (int*)take((size_t)NN * sizeof(int));
  int* rowptr    = (int*)take((size_t)(NN + 1) * sizeof(int));
  int* poscur    = (int*)take((size_t)NN * sizeof(int));
  int* bhist     = (int*)take((size_t)NSB * RR * sizeof(int));
  int* boff      = (int*)take((size_t)NSB * RR * sizeof(int));
  int* bsum      = (int*)take((size_t)SCAN_NB * sizeof(int));
  int* osrc      = (int*)take((size_t)EE * sizeof(int));
  int* opos      = (int*)take((size_t)EE * sizeof(int));
  float* oscale  = (float*)take((size_t)EE * sizeof(float));
  int4* chunkArr = (int4*)take((size_t)MAXCHUNKS * sizeof(int4));
  int* nchunks   = (int*)take(256);
  const size_t base_off = off;                         // tier-2 requirement
  float* rt      = (float*)take((size_t)NN * DIM * sizeof(float));
  float* rs      = (float*)take((size_t)NN * DIM * sizeof(float));
  int* cnt       = (int*)m;  // alias: cnt only needed before msg_k writes m

  if (base_off <= ws_size) {
    // ---- sorted path ----
    hipMemsetAsync(cnt, 0, (size_t)NN * RR * sizeof(int), stream);
    hipMemsetAsync(deg, 0, (size_t)NN * sizeof(int), stream);

    hist_k<<<NSB, 256, 0, stream>>>(dstp, et, cnt, deg, bhist, EE);
    scan1_k<<<SCAN_NB, 1024, 0, stream>>>(deg, bsum);
    scan2_k<<<1, 64, 0, stream>>>(bsum);
    scan3_k<<<SCAN_NB, 1024, 0, stream>>>(deg, bsum, rowptr, poscur);
    scan_type_k<<<1, 128, 0, stream>>>(bhist, boff, chunkArr, nchunks);
    scatter_k<<<NSB, 256, 0, stream>>>(src, dstp, et, cnt, boff, poscur,
                                       osrc, opos, oscale, EE);

    const int XG = (NN + XNB - 1) / XNB;  // 782
    if (off <= ws_size) {
      // tier 1: split transform + streaming epilogue
      // layer 0: x -> h1
      msg_k<<<MAXCHUNKS, 256, 0, stream>>>(x, osrc, opos, oscale, W, chunkArr, nchunks, m);
      xform_k<<<XG, 256, 0, stream>>>(x, root, bias, resW, resb, rt, rs, NN);
      gather2_k<<<(NN + 15) / 16, 256, 0, stream>>>(m, rowptr, rt, rs, h1, NN);
      // layer 1: h1 -> out
      msg_k<<<MAXCHUNKS, 256, 0, stream>>>(h1, osrc, opos, oscale,
                                           W + (size_t)RR * DIM * DIM, chunkArr, nchunks, m);
      xform_k<<<XG, 256, 0, stream>>>(h1, root + DIM * DIM, bias + DIM,
                                      resW + DIM * DIM, resb + DIM, rt, rs, NN);
      gather2_k<<<(NN + 15) / 16, 256, 0, stream>>>(m, rowptr, rt, rs, out, NN);
    } else {
      // tier 2: round-4 fused gather
      msg_k<<<MAXCHUNKS, 256, 0, stream>>>(x, osrc, opos, oscale, W, chunkArr, nchunks, m);
      gather_k<<<(NN + 15) / 16, 256, 0, stream>>>(x, m, rowptr, root, bias, resW, resb, h1, NN);
      msg_k<<<MAXCHUNKS, 256, 0, stream>>>(h1, osrc, opos, oscale,
                                           W + (size_t)RR * DIM * DIM, chunkArr, nchunks, m);
      gather_k<<<(NN + 15) / 16, 256, 0, stream>>>(h1, m, rowptr, root + DIM * DIM, bias + DIM,
                                                   resW + DIM * DIM, resb + DIM, out, NN);
    }
  } else {
    // ---- tier 3: atomic path (needs only 25.8 MB) ----
    int* fcnt = (int*)ws;
    float* fh1 = (float*)(ws + (size_t)NN * RR * sizeof(int));
    hipMemsetAsync(fcnt, 0, (size_t)NN * RR * sizeof(int), stream);
    hipMemsetAsync(fh1, 0, (size_t)NN * DIM * sizeof(float), stream);
    hipMemsetAsync(out, 0, (size_t)NN * DIM * sizeof(float), stream);
    count_k<<<(EE + 255) / 256, 256, 0, stream>>>(dstp, et, fcnt, EE);
    edge_k<<<(EE + 15) / 16, 256, 0, stream>>>(x, src, dstp, et, W, fcnt, fh1, EE);
    node_k<<<(NN + 15) / 16, 256, 0, stream>>>(x, root, bias, resW, resb, fh1, NN);
    edge_k<<<(EE + 15) / 16, 256, 0, stream>>>(fh1, src, dstp, et,
                                               W + (size_t)RR * DIM * DIM, fcnt, out, EE);
    node_k<<<(NN + 15) / 16, 256, 0, stream>>>(fh1, root + DIM * DIM, bias + DIM,
                                               resW + DIM * DIM, resb + DIM, out, NN);
  }
}

// Round 6
// 272.970 us; speedup vs baseline: 5.3555x; 1.2563x over previous
//
#include <hip/hip_runtime.h>

// RGCN: N=50000, E=600000, D=64, R=65, L=2.
// out_i = relu( sum_r mean_{j in N_r(i)} x_j@W_r + x_i@root + b ) + relu( x_i@res_W + res_b )
// Counting-sort edges by relation (block-histogram sort) and by dst. Per-edge
// transform now via MFMA (bf16 in, f32 acc): C' = W^T x^T per 256-edge chunk,
// A=WT staged in LDS (padded), B=gathered bf16 h rows, C packs 4 consecutive
// msg cols per lane -> 8B stores. Node transforms dense in xform_k; streaming
// CSR epilogue gather2_k.

constexpr int NN  = 50000;
constexpr int EE  = 600000;
constexpr int DIM = 64;
constexpr int RR  = 65;
constexpr int CHUNK = 256;                        // edges per relation-chunk
constexpr int MAXCHUNKS = EE / CHUNK + RR + 8;
constexpr int SORT_BS = 4096;                     // edges per sort block
constexpr int NSB = (EE + SORT_BS - 1) / SORT_BS; // 147
constexpr int SCAN_BS = 1024;
constexpr int SCAN_NB = (NN + SCAN_BS - 1) / SCAN_BS; // 49
constexpr int XNB = 64;                           // nodes per xform block

typedef __attribute__((ext_vector_type(8))) short short8v;
typedef __attribute__((ext_vector_type(4))) float floatx4;

__device__ inline unsigned short f2bf(float f) {
  unsigned int u = __float_as_uint(f);
  return (unsigned short)((u + 0x7fffu + ((u >> 16) & 1u)) >> 16);  // RNE
}
__device__ inline float bf2f(unsigned short v) {
  return __uint_as_float(((unsigned int)v) << 16);
}

// ---------------- setup (layer-invariant, rebuilt every launch) ----------------

__global__ __launch_bounds__(256) void hist_k(const int* __restrict__ dst,
                                              const int* __restrict__ et,
                                              int* __restrict__ cnt,
                                              int* __restrict__ deg,
                                              int* __restrict__ bhist, int E) {
  __shared__ int lh[RR];
  for (int i = threadIdx.x; i < RR; i += 256) lh[i] = 0;
  __syncthreads();
  const int base = blockIdx.x * SORT_BS;
  for (int i = threadIdx.x; i < SORT_BS; i += 256) {
    const int e = base + i;
    if (e < E) {
      const int d = dst[e], r = et[e];
      atomicAdd(&lh[r], 1);                  // LDS, block-local
      atomicAdd(&cnt[d * RR + r], 1);        // 3.25M addrs, uncontended
      atomicAdd(&deg[d], 1);                 // 50k addrs, ~12 avg
    }
  }
  __syncthreads();
  for (int i = threadIdx.x; i < RR; i += 256) bhist[blockIdx.x * RR + i] = lh[i];
}

// ---- parallel exclusive scan of deg[NN] -> rowptr, poscur ----

__global__ __launch_bounds__(1024) void scan1_k(const int* __restrict__ deg,
                                                int* __restrict__ bsum) {
  __shared__ int s[SCAN_BS];
  const int idx = blockIdx.x * SCAN_BS + threadIdx.x;
  s[threadIdx.x] = (idx < NN) ? deg[idx] : 0;
  __syncthreads();
  for (int off = SCAN_BS / 2; off > 0; off >>= 1) {
    if (threadIdx.x < off) s[threadIdx.x] += s[threadIdx.x + off];
    __syncthreads();
  }
  if (threadIdx.x == 0) bsum[blockIdx.x] = s[0];
}

__global__ __launch_bounds__(64) void scan2_k(int* __restrict__ bsum) {
  if (threadIdx.x == 0) {
    int run = 0;
    for (int b = 0; b < SCAN_NB; ++b) { const int v = bsum[b]; bsum[b] = run; run += v; }
  }
}

__global__ __launch_bounds__(1024) void scan3_k(const int* __restrict__ deg,
                                                const int* __restrict__ bsum,
                                                int* __restrict__ rowptr,
                                                int* __restrict__ poscur) {
  __shared__ int s[SCAN_BS];
  const int t = threadIdx.x;
  const int idx = blockIdx.x * SCAN_BS + t;
  const int v = (idx < NN) ? deg[idx] : 0;
  s[t] = v;
  __syncthreads();
  for (int off = 1; off < SCAN_BS; off <<= 1) {  // Hillis-Steele inclusive
    const int u = (t >= off) ? s[t - off] : 0;
    __syncthreads();
    s[t] += u;
    __syncthreads();
  }
  const int excl = bsum[blockIdx.x] + s[t] - v;
  if (idx < NN) { rowptr[idx] = excl; poscur[idx] = excl; }
  if (idx == NN - 1) rowptr[NN] = EE;
}

__global__ __launch_bounds__(128) void scan_type_k(const int* __restrict__ bhist,
                                                   int* __restrict__ boff,
                                                   int4* __restrict__ chunkArr,
                                                   int* __restrict__ nchunks) {
  __shared__ int total[RR], tptr[RR + 1], chbase[RR + 1];
  const int t = threadIdx.x;
  if (t < RR) {
    int s = 0;
    for (int b = 0; b < NSB; ++b) s += bhist[b * RR + t];
    total[t] = s;
  }
  __syncthreads();
  if (t == 0) {
    int run = 0, crun = 0;
    for (int r = 0; r < RR; ++r) {
      tptr[r] = run;   run  += total[r];
      chbase[r] = crun; crun += (total[r] + CHUNK - 1) / CHUNK;
    }
    tptr[RR] = run; chbase[RR] = crun;
    *nchunks = crun;
  }
  __syncthreads();
  if (t < RR) {
    int run = tptr[t];
    for (int b = 0; b < NSB; ++b) { boff[b * RR + t] = run; run += bhist[b * RR + t]; }
    const int nc = (total[t] + CHUNK - 1) / CHUNK;
    for (int i = 0; i < nc; ++i) {
      const int beg = tptr[t] + i * CHUNK;
      chunkArr[chbase[t] + i] = make_int4(beg, min(beg + CHUNK, tptr[t] + total[t]), t, 0);
    }
  }
}

__global__ __launch_bounds__(256) void scatter_k(const int* __restrict__ src,
                                                 const int* __restrict__ dst,
                                                 const int* __restrict__ et,
                                                 const int* __restrict__ cnt,
                                                 const int* __restrict__ boff,
                                                 int* __restrict__ poscur,
                                                 int* __restrict__ osrc,
                                                 int* __restrict__ opos,
                                                 float* __restrict__ oscale, int E) {
  __shared__ int cur[RR];
  for (int i = threadIdx.x; i < RR; i += 256) cur[i] = boff[blockIdx.x * RR + i];
  __syncthreads();
  const int base = blockIdx.x * SORT_BS;
  for (int i = threadIdx.x; i < SORT_BS; i += 256) {
    const int e = base + i;
    if (e < E) {
      const int s = src[e], d = dst[e], r = et[e];
      const int q = atomicAdd(&cur[r], 1);       // LDS atomic, block-local
      const int p = atomicAdd(&poscur[d], 1);    // global, ~12 avg contention
      osrc[q] = s;
      opos[q] = p;
      oscale[q] = 1.0f / (float)cnt[d * RR + r];
    }
  }
}

// ---------------- bf16 conversion kernels ----------------

// W[l][r][k][c] f32 -> WT[l*R+r][c][k] bf16 (transposed), both layers at once.
__global__ __launch_bounds__(256) void cvtw_k(const float* __restrict__ W,
                                              unsigned short* __restrict__ WT) {
  const int tid = blockIdx.x * 256 + threadIdx.x;     // one float4 per thread
  const int total4 = 2 * RR * DIM * DIM / 4;          // 133120
  if (tid >= total4) return;
  const int base = tid * 4;
  const int mat = base >> 12;
  const int rem = base & 4095;
  const int k = rem >> 6, c0 = rem & 63;
  const float4 v = *reinterpret_cast<const float4*>(W + base);
  unsigned short* o = WT + (size_t)mat * 4096;
  o[(c0 + 0) * 64 + k] = f2bf(v.x);
  o[(c0 + 1) * 64 + k] = f2bf(v.y);
  o[(c0 + 2) * 64 + k] = f2bf(v.z);
  o[(c0 + 3) * 64 + k] = f2bf(v.w);
}

__global__ __launch_bounds__(256) void cvth_k(const float* __restrict__ h,
                                              unsigned short* __restrict__ hbf) {
  const int tid = blockIdx.x * 256 + threadIdx.x;     // 8 elems per thread
  if (tid * 8 >= NN * DIM) return;
  const float4 v0 = reinterpret_cast<const float4*>(h)[tid * 2];
  const float4 v1 = reinterpret_cast<const float4*>(h)[tid * 2 + 1];
  ushort4 a, b;
  a.x = f2bf(v0.x); a.y = f2bf(v0.y); a.z = f2bf(v0.z); a.w = f2bf(v0.w);
  b.x = f2bf(v1.x); b.y = f2bf(v1.y); b.z = f2bf(v1.z); b.w = f2bf(v1.w);
  reinterpret_cast<ushort4*>(hbf)[tid * 2] = a;
  reinterpret_cast<ushort4*>(hbf)[tid * 2 + 1] = b;
}

// ---------------- per-layer kernels ----------------

// MFMA message kernel: one block per 256-edge relation-chunk, 4 waves x 64 edges.
// C'[col][edge] = WT x^T: A-frag = WT rows (LDS, padded stride 72 ushorts),
// B-frag = gathered hbf rows. C: edge = lane&15, col = (lane>>4)*4 + j.
__global__ __launch_bounds__(256) void msgm_k(const unsigned short* __restrict__ hbf,
                                              const int* __restrict__ osrc,
                                              const int* __restrict__ opos,
                                              const float* __restrict__ oscale,
                                              const unsigned short* __restrict__ WT,
                                              const int4* __restrict__ chunkArr,
                                              const int* __restrict__ nchunks,
                                              unsigned short* __restrict__ m) {
  const int ci = blockIdx.x;
  if (ci >= *nchunks) return;
  const int4 c = chunkArr[ci];
  const int beg = c.x, end = c.y, rel = c.z;

  __shared__ unsigned short Wl[DIM][72];   // +8 pad: b128 reads hit LDS BW floor
  {
    const float4* s4 = reinterpret_cast<const float4*>(WT + (size_t)rel * 4096);
#pragma unroll
    for (int it = 0; it < 2; ++it) {
      const int seg = threadIdx.x + it * 256;   // 512 x 16B segments
      const int row = seg >> 3, s8 = seg & 7;
      *reinterpret_cast<float4*>(&Wl[row][s8 * 8]) = s4[seg];
    }
  }
  __syncthreads();

  const int w  = threadIdx.x >> 6;
  const int l  = threadIdx.x & 63;
  const int lr = l & 15, lq = l >> 4;

  const int ebase = beg + w * 64;
  if (ebase >= end) return;                // no barriers after this point

  short8v a[4][2];
#pragma unroll
  for (int ct = 0; ct < 4; ++ct)
#pragma unroll
    for (int kk = 0; kk < 2; ++kk)
      a[ct][kk] = *reinterpret_cast<const short8v*>(&Wl[ct * 16 + lr][kk * 32 + lq * 8]);

  short8v b[4][2];
  int eidx[4];
#pragma unroll
  for (int et = 0; et < 4; ++et) {
    eidx[et] = ebase + et * 16 + lr;
    const int e = min(eidx[et], end - 1);  // clamp (safe dup, store guarded)
    const int s = osrc[e];
    const unsigned short* hp = hbf + (size_t)s * DIM;
    b[et][0] = *reinterpret_cast<const short8v*>(hp + lq * 8);
    b[et][1] = *reinterpret_cast<const short8v*>(hp + 32 + lq * 8);
  }

  floatx4 acc[4][4];
#pragma unroll
  for (int ct = 0; ct < 4; ++ct)
#pragma unroll
    for (int et = 0; et < 4; ++et)
      acc[ct][et] = (floatx4){0.f, 0.f, 0.f, 0.f};

#pragma unroll
  for (int kk = 0; kk < 2; ++kk)
#pragma unroll
    for (int ct = 0; ct < 4; ++ct)
#pragma unroll
      for (int et = 0; et < 4; ++et)
        acc[ct][et] = __builtin_amdgcn_mfma_f32_16x16x32_bf16(a[ct][kk], b[et][kk],
                                                              acc[ct][et], 0, 0, 0);

#pragma unroll
  for (int et = 0; et < 4; ++et) {
    const int e = eidx[et];
    if (e < end) {
      const float sc = oscale[e];
      unsigned short* op = m + (size_t)opos[e] * DIM;
#pragma unroll
      for (int ct = 0; ct < 4; ++ct) {
        ushort4 o;
        o.x = f2bf(acc[ct][et][0] * sc);
        o.y = f2bf(acc[ct][et][1] * sc);
        o.z = f2bf(acc[ct][et][2] * sc);
        o.w = f2bf(acc[ct][et][3] * sc);
        *reinterpret_cast<ushort4*>(op + ct * 16 + lq * 4) = o;  // cols ct*16+lq*4..+3
      }
    }
  }
}

// fp32 message kernel (fallback if ws lacks room for bf16 buffers).
__global__ __launch_bounds__(256) void msg_k(const float* __restrict__ h,
                                             const int* __restrict__ osrc,
                                             const int* __restrict__ opos,
                                             const float* __restrict__ oscale,
                                             const float* __restrict__ W,
                                             const int4* __restrict__ chunkArr,
                                             const int* __restrict__ nchunks,
                                             unsigned short* __restrict__ m) {
  const int ci = blockIdx.x;
  if (ci >= *nchunks) return;
  const int4 c = chunkArr[ci];
  const int beg = c.x, end = c.y, rel = c.z;

  __shared__ float Wlds[DIM * DIM];
  const float* Wg = W + (size_t)rel * (DIM * DIM);
#pragma unroll
  for (int i = 0; i < 4; ++i)
    *reinterpret_cast<float4*>(&Wlds[i * 1024 + threadIdx.x * 4]) =
        *reinterpret_cast<const float4*>(Wg + i * 1024 + threadIdx.x * 4);
  __syncthreads();

  const int g = threadIdx.x >> 4, li = threadIdx.x & 15;
  __shared__ float xs[16][4][68];

  for (int b = 0; b < 4; ++b) {
    const int e0 = beg + g * 16 + b * 4;
    const int nvalid = min(4, end - e0);
    if (nvalid <= 0) continue;

#pragma unroll
    for (int r = 0; r < 4; ++r) {
      const int e = e0 + ((r < nvalid) ? r : (nvalid - 1));
      const int s = osrc[e];
      *reinterpret_cast<float4*>(&xs[g][r][li * 4]) =
          *reinterpret_cast<const float4*>(h + (size_t)s * DIM + li * 4);
    }

    float acc[4][4];
#pragma unroll
    for (int r = 0; r < 4; ++r) { acc[r][0] = 0.f; acc[r][1] = 0.f; acc[r][2] = 0.f; acc[r][3] = 0.f; }

#pragma unroll 8
    for (int k = 0; k < DIM; ++k) {
      const float4 w = *reinterpret_cast<const float4*>(&Wlds[k * DIM + li * 4]);
#pragma unroll
      for (int r = 0; r < 4; ++r) {
        const float xv = xs[g][r][k];
        acc[r][0] += xv * w.x; acc[r][1] += xv * w.y;
        acc[r][2] += xv * w.z; acc[r][3] += xv * w.w;
      }
    }

    for (int r = 0; r < nvalid; ++r) {
      const int e = e0 + r;
      const float sc = oscale[e];
      ushort4 o;
      o.x = f2bf(acc[r][0] * sc); o.y = f2bf(acc[r][1] * sc);
      o.z = f2bf(acc[r][2] * sc); o.w = f2bf(acc[r][3] * sc);
      *reinterpret_cast<ushort4*>(m + (size_t)opos[e] * DIM + li * 4) = o;
    }
  }
}

// Dense node transform: rt = h@root + b, rs = relu(h@rw + rb). Both matrices in LDS.
__global__ __launch_bounds__(256) void xform_k(const float* __restrict__ h,
                                               const float* __restrict__ root,
                                               const float* __restrict__ bias,
                                               const float* __restrict__ rw,
                                               const float* __restrict__ rb,
                                               float* __restrict__ rt,
                                               float* __restrict__ rs, int N) {
  __shared__ float Wl0[DIM * DIM];
  __shared__ float Wl1[DIM * DIM];
  __shared__ float xs[XNB][68];
#pragma unroll
  for (int i = 0; i < 4; ++i) {
    reinterpret_cast<float4*>(Wl0)[threadIdx.x + i * 256] =
        reinterpret_cast<const float4*>(root)[threadIdx.x + i * 256];
    reinterpret_cast<float4*>(Wl1)[threadIdx.x + i * 256] =
        reinterpret_cast<const float4*>(rw)[threadIdx.x + i * 256];
  }

  const int g = threadIdx.x >> 4, li = threadIdx.x & 15;
  const int base = blockIdx.x * XNB;
#pragma unroll
  for (int r = 0; r < 4; ++r) {
    const int n = base + g * 4 + r;
    float4 v = make_float4(0.f, 0.f, 0.f, 0.f);
    if (n < N) v = *reinterpret_cast<const float4*>(h + (size_t)n * DIM + li * 4);
    *reinterpret_cast<float4*>(&xs[g * 4 + r][li * 4]) = v;
  }
  __syncthreads();

  float aR[4][4], aS[4][4];
#pragma unroll
  for (int r = 0; r < 4; ++r)
#pragma unroll
    for (int q = 0; q < 4; ++q) { aR[r][q] = 0.f; aS[r][q] = 0.f; }

#pragma unroll 4
  for (int k = 0; k < DIM; ++k) {
    const float4 wr = *reinterpret_cast<const float4*>(&Wl0[k * DIM + li * 4]);
    const float4 wv = *reinterpret_cast<const float4*>(&Wl1[k * DIM + li * 4]);
#pragma unroll
    for (int r = 0; r < 4; ++r) {
      const float xv = xs[g * 4 + r][k];
      aR[r][0] += xv * wr.x; aR[r][1] += xv * wr.y; aR[r][2] += xv * wr.z; aR[r][3] += xv * wr.w;
      aS[r][0] += xv * wv.x; aS[r][1] += xv * wv.y; aS[r][2] += xv * wv.z; aS[r][3] += xv * wv.w;
    }
  }

  const float4 bv = reinterpret_cast<const float4*>(bias)[li];
  const float4 cv = reinterpret_cast<const float4*>(rb)[li];
#pragma unroll
  for (int r = 0; r < 4; ++r) {
    const int n = base + g * 4 + r;
    if (n < N) {
      *reinterpret_cast<float4*>(rt + (size_t)n * DIM + li * 4) =
          make_float4(aR[r][0] + bv.x, aR[r][1] + bv.y, aR[r][2] + bv.z, aR[r][3] + bv.w);
      *reinterpret_cast<float4*>(rs + (size_t)n * DIM + li * 4) =
          make_float4(fmaxf(aS[r][0] + cv.x, 0.f), fmaxf(aS[r][1] + cv.y, 0.f),
                      fmaxf(aS[r][2] + cv.z, 0.f), fmaxf(aS[r][3] + cv.w, 0.f));
    }
  }
}

// Streaming epilogue: hout = relu(sum(msgs) + rt) + rs. Msg loop unrolled 4x.
__global__ __launch_bounds__(256) void gather2_k(const unsigned short* __restrict__ m,
                                                 const int* __restrict__ rowptr,
                                                 const float* __restrict__ rt,
                                                 const float* __restrict__ rs,
                                                 float* __restrict__ hout, int N) {
  const int g = threadIdx.x >> 4, li = threadIdx.x & 15;
  const int n = blockIdx.x * 16 + g;
  if (n >= N) return;

  float a0 = 0.f, a1 = 0.f, a2 = 0.f, a3 = 0.f;
  const int jb = rowptr[n], je = rowptr[n + 1];
  int j = jb;
  for (; j + 4 <= je; j += 4) {
    const ushort4 v0 = *reinterpret_cast<const ushort4*>(m + (size_t)(j + 0) * DIM + li * 4);
    const ushort4 v1 = *reinterpret_cast<const ushort4*>(m + (size_t)(j + 1) * DIM + li * 4);
    const ushort4 v2 = *reinterpret_cast<const ushort4*>(m + (size_t)(j + 2) * DIM + li * 4);
    const ushort4 v3 = *reinterpret_cast<const ushort4*>(m + (size_t)(j + 3) * DIM + li * 4);
    a0 += bf2f(v0.x) + bf2f(v1.x) + bf2f(v2.x) + bf2f(v3.x);
    a1 += bf2f(v0.y) + bf2f(v1.y) + bf2f(v2.y) + bf2f(v3.y);
    a2 += bf2f(v0.z) + bf2f(v1.z) + bf2f(v2.z) + bf2f(v3.z);
    a3 += bf2f(v0.w) + bf2f(v1.w) + bf2f(v2.w) + bf2f(v3.w);
  }
  for (; j < je; ++j) {
    const ushort4 v = *reinterpret_cast<const ushort4*>(m + (size_t)j * DIM + li * 4);
    a0 += bf2f(v.x); a1 += bf2f(v.y); a2 += bf2f(v.z); a3 += bf2f(v.w);
  }

  const float4 t = *reinterpret_cast<const float4*>(rt + (size_t)n * DIM + li * 4);
  const float4 s = *reinterpret_cast<const float4*>(rs + (size_t)n * DIM + li * 4);
  *reinterpret_cast<float4*>(hout + (size_t)n * DIM + li * 4) =
      make_float4(fmaxf(a0 + t.x, 0.f) + s.x, fmaxf(a1 + t.y, 0.f) + s.y,
                  fmaxf(a2 + t.z, 0.f) + s.z, fmaxf(a3 + t.w, 0.f) + s.w);
}

// Fused fallback gather (round-4 path, used if ws lacks room for rt/rs).
__global__ __launch_bounds__(256) void gather_k(const float* __restrict__ hin,
                                                const unsigned short* __restrict__ m,
                                                const int* __restrict__ rowptr,
                                                const float* __restrict__ root,
                                                const float* __restrict__ bias,
                                                const float* __restrict__ rw,
                                                const float* __restrict__ rb,
                                                float* __restrict__ hout, int N) {
  __shared__ float xs[16][68];
  const int g = threadIdx.x >> 4, li = threadIdx.x & 15;
  const int n = blockIdx.x * 16 + g;
  if (n >= N) return;

  *reinterpret_cast<float4*>(&xs[g][li * 4]) =
      *reinterpret_cast<const float4*>(hin + (size_t)n * DIM + li * 4);

  float a0 = 0.f, a1 = 0.f, a2 = 0.f, a3 = 0.f;
  const int jb = rowptr[n], je = rowptr[n + 1];
  for (int j = jb; j < je; ++j) {
    const ushort4 mv = *reinterpret_cast<const ushort4*>(m + (size_t)j * DIM + li * 4);
    a0 += bf2f(mv.x); a1 += bf2f(mv.y); a2 += bf2f(mv.z); a3 += bf2f(mv.w);
  }

  float r0 = 0.f, r1 = 0.f, r2 = 0.f, r3 = 0.f;
  float s0 = 0.f, s1 = 0.f, s2 = 0.f, s3 = 0.f;
#pragma unroll 8
  for (int k = 0; k < DIM; ++k) {
    const float hd = xs[g][k];
    const float4 w = *reinterpret_cast<const float4*>(root + k * DIM + li * 4);
    const float4 v = *reinterpret_cast<const float4*>(rw + k * DIM + li * 4);
    r0 += hd * w.x; r1 += hd * w.y; r2 += hd * w.z; r3 += hd * w.w;
    s0 += hd * v.x; s1 += hd * v.y; s2 += hd * v.z; s3 += hd * v.w;
  }
  const float4 b = *reinterpret_cast<const float4*>(bias + li * 4);
  const float4 cc = *reinterpret_cast<const float4*>(rb + li * 4);
  float o0 = fmaxf(a0 + r0 + b.x, 0.f) + fmaxf(s0 + cc.x, 0.f);
  float o1 = fmaxf(a1 + r1 + b.y, 0.f) + fmaxf(s1 + cc.y, 0.f);
  float o2 = fmaxf(a2 + r2 + b.z, 0.f) + fmaxf(s2 + cc.z, 0.f);
  float o3 = fmaxf(a3 + r3 + b.w, 0.f) + fmaxf(s3 + cc.w, 0.f);
  *reinterpret_cast<float4*>(hout + (size_t)n * DIM + li * 4) = make_float4(o0, o1, o2, o3);
}

// ---------------- last-resort fallback (float atomics) ----------------

__global__ __launch_bounds__(256) void count_k(const int* __restrict__ dst,
                                               const int* __restrict__ et,
                                               int* __restrict__ cnt, int E) {
  int e = blockIdx.x * 256 + threadIdx.x;
  if (e < E) atomicAdd(&cnt[dst[e] * RR + et[e]], 1);
}

__global__ __launch_bounds__(256) void edge_k(const float* __restrict__ h,
                                              const int* __restrict__ src,
                                              const int* __restrict__ dst,
                                              const int* __restrict__ et,
                                              const float* __restrict__ W,
                                              const int* __restrict__ cnt,
                                              float* __restrict__ accum, int E) {
  __shared__ float xs[16][68];
  const int g = threadIdx.x >> 4, li = threadIdx.x & 15;
  const int e = blockIdx.x * 16 + g;
  if (e >= E) return;
  const int s = src[e], d = dst[e], t = et[e];
  *reinterpret_cast<float4*>(&xs[g][li * 4]) =
      *reinterpret_cast<const float4*>(h + (size_t)s * DIM + li * 4);
  const float* Wt = W + (size_t)t * (DIM * DIM) + li * 4;
  float a0 = 0.f, a1 = 0.f, a2 = 0.f, a3 = 0.f;
#pragma unroll 8
  for (int k = 0; k < DIM; ++k) {
    const float xd = xs[g][k];
    const float4 w = *reinterpret_cast<const float4*>(Wt + k * DIM);
    a0 += xd * w.x; a1 += xd * w.y; a2 += xd * w.z; a3 += xd * w.w;
  }
  const float sc = 1.0f / (float)cnt[d * RR + t];
  float* o = accum + (size_t)d * DIM + li * 4;
  unsafeAtomicAdd(o + 0, a0 * sc);
  unsafeAtomicAdd(o + 1, a1 * sc);
  unsafeAtomicAdd(o + 2, a2 * sc);
  unsafeAtomicAdd(o + 3, a3 * sc);
}

__global__ __launch_bounds__(256) void node_k(const float* __restrict__ h,
                                              const float* __restrict__ root,
                                              const float* __restrict__ bias,
                                              const float* __restrict__ rw,
                                              const float* __restrict__ rb,
                                              float* __restrict__ io, int N) {
  __shared__ float xs[16][68];
  const int g = threadIdx.x >> 4, li = threadIdx.x & 15;
  const int n = blockIdx.x * 16 + g;
  if (n >= N) return;
  *reinterpret_cast<float4*>(&xs[g][li * 4]) =
      *reinterpret_cast<const float4*>(h + (size_t)n * DIM + li * 4);
  float r0 = 0.f, r1 = 0.f, r2 = 0.f, r3 = 0.f;
  float s0 = 0.f, s1 = 0.f, s2 = 0.f, s3 = 0.f;
#pragma unroll 8
  for (int k = 0; k < DIM; ++k) {
    const float hd = xs[g][k];
    const float4 w = *reinterpret_cast<const float4*>(root + k * DIM + li * 4);
    const float4 v = *reinterpret_cast<const float4*>(rw + k * DIM + li * 4);
    r0 += hd * w.x; r1 += hd * w.y; r2 += hd * w.z; r3 += hd * w.w;
    s0 += hd * v.x; s1 += hd * v.y; s2 += hd * v.z; s3 += hd * v.w;
  }
  float* o = io + (size_t)n * DIM + li * 4;
  const float4 acc = *reinterpret_cast<const float4*>(o);
  const float4 b = *reinterpret_cast<const float4*>(bias + li * 4);
  const float4 c = *reinterpret_cast<const float4*>(rb + li * 4);
  float o0 = fmaxf(acc.x + r0 + b.x, 0.f) + fmaxf(s0 + c.x, 0.f);
  float o1 = fmaxf(acc.y + r1 + b.y, 0.f) + fmaxf(s1 + c.y, 0.f);
  float o2 = fmaxf(acc.z + r2 + b.z, 0.f) + fmaxf(s2 + c.z, 0.f);
  float o3 = fmaxf(acc.w + r3 + b.w, 0.f) + fmaxf(s3 + c.w, 0.f);
  *reinterpret_cast<float4*>(o) = make_float4(o0, o1, o2, o3);
}

// ---------------- host ----------------

extern "C" void kernel_launch(void* const* d_in, const int* in_sizes, int n_in,
                              void* d_out, int out_size, void* d_ws, size_t ws_size,
                              hipStream_t stream) {
  const float* x    = (const float*)d_in[0];
  const int*   ei   = (const int*)d_in[1];
  const int*   et   = (const int*)d_in[2];
  const float* W    = (const float*)d_in[3];
  const float* root = (const float*)d_in[4];
  const float* bias = (const float*)d_in[5];
  const float* resW = (const float*)d_in[6];
  const float* resb = (const float*)d_in[7];
  float* out = (float*)d_out;

  const int* src = ei;
  const int* dstp = ei + EE;

  char* ws = (char*)d_ws;
  size_t off = 0;
  auto take = [&](size_t bytes) -> void* {
    void* p = ws + off;
    off = (off + bytes + 255) & ~(size_t)255;
    return p;
  };
  unsigned short* m = (unsigned short*)take((size_t)EE * DIM * sizeof(unsigned short));
  float* h1      = (float*)take((size_t)NN * DIM * sizeof(float));
  int* deg       = (int*)take((size_t)NN * sizeof(int));
  int* rowptr    = (int*)take((size_t)(NN + 1) * sizeof(int));
  int* poscur    = (int*)take((size_t)NN * sizeof(int));
  int* bhist     = (int*)take((size_t)NSB * RR * sizeof(int));
  int* boff      = (int*)take((size_t)NSB * RR * sizeof(int));
  int* bsum      = (int*)take((size_t)SCAN_NB * sizeof(int));
  int* osrc      = (int*)take((size_t)EE * sizeof(int));
  int* opos      = (int*)take((size_t)EE * sizeof(int));
  float* oscale  = (float*)take((size_t)EE * sizeof(float));
  int4* chunkArr = (int4*)take((size_t)MAXCHUNKS * sizeof(int4));
  int* nchunks   = (int*)take(256);
  const size_t base_off = off;                          // tier-2 requirement
  float* rt      = (float*)take((size_t)NN * DIM * sizeof(float));
  float* rs      = (float*)take((size_t)NN * DIM * sizeof(float));
  const size_t t1_off = off;                            // tier-1 requirement
  unsigned short* hbf = (unsigned short*)take((size_t)NN * DIM * sizeof(unsigned short));
  unsigned short* wbt = (unsigned short*)take((size_t)2 * RR * DIM * DIM * sizeof(unsigned short));
  const size_t mfma_off = off;                          // tier-1-MFMA requirement
  int* cnt       = (int*)m;  // alias: cnt only needed before msg writes m

  if (base_off <= ws_size) {
    // ---- sorted path ----
    hipMemsetAsync(cnt, 0, (size_t)NN * RR * sizeof(int), stream);
    hipMemsetAsync(deg, 0, (size_t)NN * sizeof(int), stream);

    hist_k<<<NSB, 256, 0, stream>>>(dstp, et, cnt, deg, bhist, EE);
    scan1_k<<<SCAN_NB, 1024, 0, stream>>>(deg, bsum);
    scan2_k<<<1, 64, 0, stream>>>(bsum);
    scan3_k<<<SCAN_NB, 1024, 0, stream>>>(deg, bsum, rowptr, poscur);
    scan_type_k<<<1, 128, 0, stream>>>(bhist, boff, chunkArr, nchunks);
    scatter_k<<<NSB, 256, 0, stream>>>(src, dstp, et, cnt, boff, poscur,
                                       osrc, opos, oscale, EE);

    const int XG = (NN + XNB - 1) / XNB;
    const int HG = (NN * DIM / 8 + 255) / 256;
    if (mfma_off <= ws_size) {
      // tier 1-MFMA: bf16 matrix-core message kernel
      cvtw_k<<<(2 * RR * DIM * DIM / 4 + 255) / 256, 256, 0, stream>>>(W, wbt);
      // layer 0: x -> h1
      cvth_k<<<HG, 256, 0, stream>>>(x, hbf);
      msgm_k<<<MAXCHUNKS, 256, 0, stream>>>(hbf, osrc, opos, oscale, wbt, chunkArr, nchunks, m);
      xform_k<<<XG, 256, 0, stream>>>(x, root, bias, resW, resb, rt, rs, NN);
      gather2_k<<<(NN + 15) / 16, 256, 0, stream>>>(m, rowptr, rt, rs, h1, NN);
      // layer 1: h1 -> out
      cvth_k<<<HG, 256, 0, stream>>>(h1, hbf);
      msgm_k<<<MAXCHUNKS, 256, 0, stream>>>(hbf, osrc, opos, oscale,
                                            wbt + (size_t)RR * DIM * DIM, chunkArr, nchunks, m);
      xform_k<<<XG, 256, 0, stream>>>(h1, root + DIM * DIM, bias + DIM,
                                      resW + DIM * DIM, resb + DIM, rt, rs, NN);
      gather2_k<<<(NN + 15) / 16, 256, 0, stream>>>(m, rowptr, rt, rs, out, NN);
    } else if (t1_off <= ws_size) {
      // tier 1: fp32 msg + split transform
      msg_k<<<MAXCHUNKS, 256, 0, stream>>>(x, osrc, opos, oscale, W, chunkArr, nchunks, m);
      xform_k<<<XG, 256, 0, stream>>>(x, root, bias, resW, resb, rt, rs, NN);
      gather2_k<<<(NN + 15) / 16, 256, 0, stream>>>(m, rowptr, rt, rs, h1, NN);
      msg_k<<<MAXCHUNKS, 256, 0, stream>>>(h1, osrc, opos, oscale,
                                           W + (size_t)RR * DIM * DIM, chunkArr, nchunks, m);
      xform_k<<<XG, 256, 0, stream>>>(h1, root + DIM * DIM, bias + DIM,
                                      resW + DIM * DIM, resb + DIM, rt, rs, NN);
      gather2_k<<<(NN + 15) / 16, 256, 0, stream>>>(m, rowptr, rt, rs, out, NN);
    } else {
      // tier 2: fused gather
      msg_k<<<MAXCHUNKS, 256, 0, stream>>>(x, osrc, opos, oscale, W, chunkArr, nchunks, m);
      gather_k<<<(NN + 15) / 16, 256, 0, stream>>>(x, m, rowptr, root, bias, resW, resb, h1, NN);
      msg_k<<<MAXCHUNKS, 256, 0, stream>>>(h1, osrc, opos, oscale,
                                           W + (size_t)RR * DIM * DIM, chunkArr, nchunks, m);
      gather_k<<<(NN + 15) / 16, 256, 0, stream>>>(h1, m, rowptr, root + DIM * DIM, bias + DIM,
                                                   resW + DIM * DIM, resb + DIM, out, NN);
    }
  } else {
    // ---- tier 3: atomic path (needs only 25.8 MB) ----
    int* fcnt = (int*)ws;
    float* fh1 = (float*)(ws + (size_t)NN * RR * sizeof(int));
    hipMemsetAsync(fcnt, 0, (size_t)NN * RR * sizeof(int), stream);
    hipMemsetAsync(fh1, 0, (size_t)NN * DIM * sizeof(float), stream);
    hipMemsetAsync(out, 0, (size_t)NN * DIM * sizeof(float), stream);
    count_k<<<(EE + 255) / 256, 256, 0, stream>>>(dstp, et, fcnt, EE);
    edge_k<<<(EE + 15) / 16, 256, 0, stream>>>(x, src, dstp, et, W, fcnt, fh1, EE);
    node_k<<<(NN + 15) / 16, 256, 0, stream>>>(x, root, bias, resW, resb, fh1, NN);
    edge_k<<<(EE + 15) / 16, 256, 0, stream>>>(fh1, src, dstp, et,
                                               W + (size_t)RR * DIM * DIM, fcnt, out, EE);
    node_k<<<(NN + 15) / 16, 256, 0, stream>>>(fh1, root + DIM * DIM, bias + DIM,
                                               resW + DIM * DIM, resb + DIM, out, NN);
  }
}